// Round 10
// baseline (311.309 us; speedup 1.0000x reference)
//
#include <hip/hip_runtime.h>

// ---- problem constants ----
#define B_   2
#define L_   4096
#define DM   768
#define DI   1536     // D_INNER
#define DS   64       // D_STATE
#define H_   24       // NHEADS
#define P_   64       // HEADDIM
#define CD   1664     // CONV_DIM
#define NPJ  3224     // D_IN_PROJ
#define N1   3200     // GEMM1 useful cols (z + xBC; dt cols done exactly in k_dt2)
#define Q_   64       // chunk length
#define NC   64       // chunks per batch
#define SP   76       // LDS row stride (floats) for k_inter tiles
#define HS   72       // fp16 LDS row stride (halves): <=2-way conflicts
#define WDS  772      // k_dt2 LDS W stride (772%32=4 -> 3-way max bank aliasing)
#define CROWS 16      // conv rows per thread

typedef short          bf16x8 __attribute__((ext_vector_type(8)));
typedef _Float16       f16x8  __attribute__((ext_vector_type(8)));
typedef _Float16       f16x4  __attribute__((ext_vector_type(4)));
typedef unsigned short us8    __attribute__((ext_vector_type(8)));
typedef unsigned short us4    __attribute__((ext_vector_type(4)));
typedef float          f32x4  __attribute__((ext_vector_type(4)));

__device__ __forceinline__ unsigned short f2bf(float f) {
  unsigned u = __float_as_uint(f);
  u += 0x7fffu + ((u >> 16) & 1u);   // RNE
  return (unsigned short)(u >> 16);
}
__device__ __forceinline__ float bf2f(unsigned short u) {
  return __uint_as_float(((unsigned)u) << 16);
}
__device__ __forceinline__ float siluf(float x) { return x / (1.f + expf(-x)); }
__device__ __forceinline__ float softplusf(float x) { return (x > 20.f) ? x : log1pf(expf(x)); }

// async global->LDS, 16B per lane; LDS dest = uniform base + lane*16
__device__ __forceinline__ void gload16(const unsigned short* g, unsigned short* l) {
  __builtin_amdgcn_global_load_lds(
      (const __attribute__((address_space(1))) void*)g,
      (__attribute__((address_space(3))) void*)l, 16, 0, 0);
}

// ---------------- transpose + cast (R x C fp32) -> (C x R bf16) ----------------
__global__ __launch_bounds__(256)
void k_transpose_cast(const float* __restrict__ src, unsigned short* __restrict__ dst,
                      int R, int C)
{
  __shared__ float tile[32][33];
  const int tx = threadIdx.x & 31, ty = threadIdx.x >> 5;
  const int r0 = blockIdx.x * 32, c0 = blockIdx.y * 32;
#pragma unroll
  for (int r = 0; r < 4; ++r) {
    int rr = r0 + ty + r * 8, cc = c0 + tx;
    if (rr < R && cc < C) tile[ty + r * 8][tx] = src[(size_t)rr * C + cc];
  }
  __syncthreads();
#pragma unroll
  for (int r = 0; r < 4; ++r) {
    int orow = c0 + ty + r * 8, ocol = r0 + tx;
    if (orow < C && ocol < R) dst[(size_t)orow * R + ocol] = f2bf(tile[tx][ty + r * 8]);
  }
}

// ---------------- gather dt columns of W_in -> contiguous fp32 WdtT[24][768] ----------------
__global__ void k_wdtT(const float* __restrict__ W_in, float* __restrict__ WdtT)
{
  const int idx = blockIdx.x * 256 + threadIdx.x;
  if (idx >= H_ * DM) return;
  const int k = idx / H_, h = idx % H_;
  WdtT[(size_t)h * DM + k] = W_in[(size_t)k * NPJ + N1 + h];
}

// ---------------- bf16 MFMA GEMM, BK=64, XOR-swizzled LDS (conflict-free) ----------------
// in-proj <256,128,64,64>@512thr (r6: 50.9us); out-proj <128,64,64,32>@256thr
// (768 blocks = 3 even rounds). r6 lesson: tiles must divide the grid evenly.
template<int BM, int BN, int WM, int WN, bool OUT_BF16>
__global__ __launch_bounds__((BM / WM) * (BN / WN) * 64)
void k_gemm_t(const unsigned short* __restrict__ A, const unsigned short* __restrict__ Bt,
              void* __restrict__ C0v, int ld0, int ncol0,
              void* __restrict__ C1v, int ld1, int K)
{
  constexpr int MI = WM / 16, NI = WN / 16;
  constexpr int WAVES_N = BN / WN;
  constexpr int T  = (BM / WM) * (BN / WN) * 64;  // threads
  constexpr int RG = T / 8;                       // rows per gload band (T*16B / 128B row)
  constexpr int RA = BM / RG, RB = BN / RG;
  const int m0 = blockIdx.x * BM, n0 = blockIdx.y * BN;
  __shared__ unsigned short As[BM][64];
  __shared__ unsigned short Bs[BN][64];
  const int tid  = threadIdx.x;
  const int wave = tid >> 6, lane = tid & 63;
  const int quad = lane >> 4, r16 = lane & 15;
  const int wm = (wave / WAVES_N) * WM, wn = (wave % WAVES_N) * WN;

  const int lr8 = lane >> 3;                                // 0..7 row-in-band
  const int csw = ((lane & 7) ^ lr8) * 8;                   // swizzled source col (shorts)
  const unsigned short* gA = A  + (size_t)(m0 + wave * 8 + lr8) * K + csw;
  const unsigned short* gB = Bt + (size_t)(n0 + wave * 8 + lr8) * K + csw;
  unsigned short* lA = &As[wave * 8][0] + (size_t)lane * 8; // +lane*16B
  unsigned short* lB = &Bs[wave * 8][0] + (size_t)lane * 8;

  f32x4 acc[MI][NI];
#pragma unroll
  for (int mi = 0; mi < MI; ++mi)
#pragma unroll
    for (int ni = 0; ni < NI; ++ni) acc[mi][ni] = (f32x4){0.f, 0.f, 0.f, 0.f};

  for (int k0 = 0; k0 < K; k0 += 64) {
#pragma unroll
    for (int r = 0; r < RA; ++r)
      gload16(gA + (size_t)(r * RG) * K + k0, lA + (size_t)r * RG * 64);
#pragma unroll
    for (int r = 0; r < RB; ++r)
      gload16(gB + (size_t)(r * RG) * K + k0, lB + (size_t)r * RG * 64);
    __syncthreads();
    bf16x8 af[MI][2], bfr[NI][2];
#pragma unroll
    for (int mi = 0; mi < MI; ++mi)
#pragma unroll
      for (int ks = 0; ks < 2; ++ks)
        af[mi][ks] = *(const bf16x8*)&As[wm + mi * 16 + r16][((quad + ks * 4) ^ (r16 & 7)) * 8];
#pragma unroll
    for (int ni = 0; ni < NI; ++ni)
#pragma unroll
      for (int ks = 0; ks < 2; ++ks)
        bfr[ni][ks] = *(const bf16x8*)&Bs[wn + ni * 16 + r16][((quad + ks * 4) ^ (r16 & 7)) * 8];
#pragma unroll
    for (int mi = 0; mi < MI; ++mi)
#pragma unroll
      for (int ni = 0; ni < NI; ++ni)
#pragma unroll
        for (int ks = 0; ks < 2; ++ks)
          acc[mi][ni] = __builtin_amdgcn_mfma_f32_16x16x32_bf16(
              af[mi][ks], bfr[ni][ks], acc[mi][ni], 0, 0, 0);
    __syncthreads();
  }
#pragma unroll
  for (int mi = 0; mi < MI; ++mi)
#pragma unroll
    for (int ni = 0; ni < NI; ++ni) {
      int col = n0 + wn + ni * 16 + r16;
      void* dst; int ld, c;
      if (col < ncol0) { dst = C0v; ld = ld0; c = col; }
      else             { dst = C1v; ld = ld1; c = col - ncol0; }
#pragma unroll
      for (int r = 0; r < 4; ++r) {
        int row = m0 + wm + mi * 16 + quad * 4 + r;
        if (OUT_BF16) ((unsigned short*)dst)[(size_t)row * ld + c] = f2bf(acc[mi][ni][r]);
        else          ((float*)dst)[(size_t)row * ld + c] = acc[mi][ni][r];
      }
    }
}

// ---------------- slim conv: only B/C channels [DI, DI+128) ----------------
// r10: the DI channels' conv is fused into k_intra (xs round-trip deleted).
__global__ __launch_bounds__(128)
void k_conv2(const unsigned short* __restrict__ xbc, const float* __restrict__ cw,
             const float* __restrict__ cb, float* __restrict__ Bm, float* __restrict__ Cm)
{
  const int ch = DI + threadIdx.x;                // 128 threads: DI..DI+127
  const int r0 = blockIdx.x * CROWS;
  const float w0 = cw[ch * 4], w1 = cw[ch * 4 + 1], w2 = cw[ch * 4 + 2], w3 = cw[ch * 4 + 3];
  const float bias = cb[ch];
  float a, b, c;
  if ((r0 & (L_ - 1)) == 0) {                 // batch start: zero history
    a = 0.f; b = 0.f; c = 0.f;
  } else {
    a = bf2f(xbc[(size_t)(r0 - 3) * CD + ch]);
    b = bf2f(xbc[(size_t)(r0 - 2) * CD + ch]);
    c = bf2f(xbc[(size_t)(r0 - 1) * CD + ch]);
  }
#pragma unroll
  for (int i = 0; i < CROWS; ++i) {
    const int lr = r0 + i;
    float d = bf2f(xbc[(size_t)lr * CD + ch]);
    float v = siluf(bias + a * w0 + b * w1 + c * w2 + d * w3);
    a = b; b = c; c = d;
    if (threadIdx.x < DS) Bm[(size_t)lr * DS + threadIdx.x] = v;
    else                  Cm[(size_t)lr * DS + (threadIdx.x - DS)] = v;
  }
}

// ---------------- exact fp32 dt, v5 (r9: ~44us) ----------------
__global__ __launch_bounds__(384)
void k_dt2(const float* __restrict__ x, const float* __restrict__ WdtT,
           const float* __restrict__ dt_bias, float* __restrict__ dtv,
           unsigned short* __restrict__ xb)
{
  __shared__ float sW[H_][WDS];
  for (int i = threadIdx.x; i < H_ * DM; i += 384)
    sW[i / DM][i % DM] = WdtT[i];
  const int h = threadIdx.x % H_, rloc = threadIdx.x / H_;   // rloc 0..15
  const int lrow = blockIdx.x * 16 + rloc;
  const float* xr = x + (size_t)lrow * DM;
  __syncthreads();
  float acc = 0.f;
#pragma unroll 8
  for (int k = 0; k < DM; k += 4) {
    f32x4 xv = *(const f32x4*)(xr + k);
    f32x4 wv = *(const f32x4*)&sW[h][k];
    acc += xv[0] * wv[0] + xv[1] * wv[1] + xv[2] * wv[2] + xv[3] * wv[3];
  }
  dtv[(size_t)lrow * H_ + h] = softplusf(acc + dt_bias[h]);
  // fused cast: 32-elem chunk per thread (L1-hot re-read); covers 16 rows x 768
  const float* xi = xr + h * 32;
  unsigned short* xo = xb + (size_t)lrow * DM + h * 32;
#pragma unroll
  for (int j = 0; j < 32; j += 8) {
    f32x4 a = *(const f32x4*)(xi + j);
    f32x4 b = *(const f32x4*)(xi + j + 4);
    us8 o;
#pragma unroll
    for (int e = 0; e < 4; ++e) { o[e] = f2bf(a[e]); o[e + 4] = f2bf(b[e]); }
    *(us8*)(xo + j) = o;
  }
}

// ---------------- intra-chunk via fp16 MFMA; ytot/Sbuf stored fp16 ----------------
// r10: depthwise conv for the DI channels is FUSED into the x-stage (reads xbc
// directly, deletes the xs round-trip: -50MB HBM). Conv math bit-identical to
// the old conv2 path (fp32 conv on bf16 xbc, one fp16 rounding into sXT).
// k_cum fused (wave-0 scan); D*x fused into the y-store.
__global__ __launch_bounds__(256)
void k_intra(const unsigned short* __restrict__ xbc, const float* __restrict__ cw,
             const float* __restrict__ cb, const float* __restrict__ Bm,
             const float* __restrict__ Cm, const float* __restrict__ dtv,
             const float* __restrict__ A_log, const float* __restrict__ Dp,
             float* __restrict__ cumA, _Float16* __restrict__ ytot,
             _Float16* __restrict__ Sbuf)
{
  const int c = blockIdx.x, h = blockIdx.y, bz = blockIdx.z;
  const int gidx = (bz * H_ + h) * NC + c;
  __shared__ _Float16 sCW[Q_][HS];   // C, then W
  __shared__ _Float16 sB [Q_][HS];
  __shared__ _Float16 sBT[Q_][HS];   // (coef_j * B[j][n]) transposed -> [n][j]
  __shared__ _Float16 sXT[Q_][HS];   // X transposed -> [p][j]
  __shared__ float scum[Q_], sdt[Q_];
  __shared__ float scw[4][Q_];       // conv weights for this head's 64 channels
  __shared__ float scb[Q_];          // conv bias
  const int tid = threadIdx.x;
  const int rowbase = bz * L_ + c * Q_;
  const int ch0 = h * P_;            // head's channel base within xbc

  {
    const int j = tid >> 2, s16 = (tid & 3) * 16;
    if (tid < Q_) {                       // wave 0 only: scan dt -> scum, emit cumA
      const float dtval = dtv[(size_t)(rowbase + tid) * H_ + h];
      sdt[tid] = dtval;
      const float A = -expf(A_log[h]);
      float v = dtval;
#pragma unroll
      for (int off = 1; off < 64; off <<= 1) {
        float o = __shfl_up(v, off, 64);
        if (tid >= off) v += o;
      }
      v *= A;
      scum[tid] = v;
      cumA[(size_t)gidx * Q_ + tid] = v;
    }
    // stage conv weights/bias for channels ch0..ch0+63 (coalesced: cw[ch0*4+tid])
    scw[tid & 3][tid >> 2] = cw[(size_t)ch0 * 4 + tid];
    if (tid < Q_) scb[tid] = cb[ch0 + tid];
    // xbc loads for conv: rows rowbase+j-3..rowbase+j, channels ch0+s16..+16
    us8 xr[4][2];
    const int rbz = bz * L_;
#pragma unroll
    for (int d = 0; d < 4; ++d) {
      const int rr = rowbase + j - 3 + d;
      const int rc = (rr < rbz) ? rbz : rr;        // clamp (loads valid ws memory)
      const unsigned short* src = xbc + (size_t)rc * CD + ch0 + s16;
      xr[d][0] = *(const us8*)src;
      xr[d][1] = *(const us8*)(src + 8);
      if (rr < rbz) {                               // zero history at batch start
        us8 z8 = {0, 0, 0, 0, 0, 0, 0, 0};
        xr[d][0] = z8; xr[d][1] = z8;
      }
    }
    f32x4 bv[4], cv[4];
    const float* bsrc = Bm + (size_t)(rowbase + j) * DS + s16;
    const float* csrc = Cm + (size_t)(rowbase + j) * DS + s16;
#pragma unroll
    for (int q = 0; q < 4; ++q) {
      bv[q] = *(const f32x4*)(bsrc + q * 4);
      cv[q] = *(const f32x4*)(csrc + q * 4);
    }
    __syncthreads();                                // covers scum, scw, scb
    const float coef = expf(scum[Q_ - 1] - scum[j]) * sdt[j];
    union { f16x8 v; _Float16 e[8]; } pc[2], pb[2];
#pragma unroll
    for (int q = 0; q < 4; ++q)
#pragma unroll
      for (int e = 0; e < 4; ++e) {
        int o = q * 4 + e;
        const int cc = s16 + o;
        pc[o >> 3].e[o & 7] = (_Float16)cv[q][e];
        pb[o >> 3].e[o & 7] = (_Float16)bv[q][e];
        sBT[cc][j] = (_Float16)(bv[q][e] * coef);
        // fused depthwise conv(4) + silu for channel ch0+cc, row rowbase+j
        float a0 = bf2f(xr[0][o >> 3][o & 7]);
        float a1 = bf2f(xr[1][o >> 3][o & 7]);
        float a2 = bf2f(xr[2][o >> 3][o & 7]);
        float a3 = bf2f(xr[3][o >> 3][o & 7]);
        float v = scb[cc] + a0 * scw[0][cc] + a1 * scw[1][cc]
                          + a2 * scw[2][cc] + a3 * scw[3][cc];
        sXT[cc][j] = (_Float16)siluf(v);
      }
    *(f16x8*)&sCW[j][s16]     = pc[0].v;
    *(f16x8*)&sCW[j][s16 + 8] = pc[1].v;
    *(f16x8*)&sB [j][s16]     = pb[0].v;
    *(f16x8*)&sB [j][s16 + 8] = pb[1].v;
  }
  __syncthreads();

  const int wave = tid >> 6, lane = tid & 63;
  const int quad = lane >> 4, r16 = lane & 15;
  const int i0 = wave * 16;
  const int irow = i0 + quad * 4;

  f32x4 g[4];
#pragma unroll
  for (int q = 0; q < 4; ++q) g[q] = (f32x4){0.f, 0.f, 0.f, 0.f};
#pragma unroll
  for (int ni = 0; ni < 4; ++ni) {
    if (ni <= wave) {
#pragma unroll
      for (int ks = 0; ks < 2; ++ks)
        g[ni] = __builtin_amdgcn_mfma_f32_16x16x32_f16(
            *(const f16x8*)&sCW[i0 + r16][ks * 32 + quad * 8],
            *(const f16x8*)&sB [ni * 16 + r16][ks * 32 + quad * 8], g[ni], 0, 0, 0);
    }
  }
  float wv[4][4];
#pragma unroll
  for (int ni = 0; ni < 4; ++ni)
#pragma unroll
    for (int r = 0; r < 4; ++r) {
      int i = irow + r, jcol = ni * 16 + r16;
      float v = 0.f;
      if (ni <= wave && jcol <= i)
        v = g[ni][r] * expf(scum[i] - scum[jcol]) * sdt[jcol];
      wv[ni][r] = v;
    }
  __syncthreads();
#pragma unroll
  for (int ni = 0; ni < 4; ++ni)
#pragma unroll
    for (int r = 0; r < 4; ++r)
      sCW[irow + r][ni * 16 + r16] = (_Float16)wv[ni][r];
  __syncthreads();

  const float Dh = Dp[h];
  f32x4 y[4];
#pragma unroll
  for (int q = 0; q < 4; ++q) y[q] = (f32x4){0.f, 0.f, 0.f, 0.f};
#pragma unroll
  for (int ni = 0; ni < 4; ++ni)
#pragma unroll
    for (int ks = 0; ks < 2; ++ks) {
      if (ks == 0 || wave >= 2)
        y[ni] = __builtin_amdgcn_mfma_f32_16x16x32_f16(
            *(const f16x8*)&sCW[i0 + r16][ks * 32 + quad * 8],
            *(const f16x8*)&sXT[ni * 16 + r16][ks * 32 + quad * 8], y[ni], 0, 0, 0);
    }
#pragma unroll
  for (int ni = 0; ni < 4; ++ni)
#pragma unroll
    for (int r = 0; r < 4; ++r) {
      const float xval = (float)sXT[ni * 16 + r16][irow + r];   // X[irow+r][ni*16+r16]
      ytot[(size_t)(rowbase + irow + r) * DI + h * P_ + ni * 16 + r16] =
          (_Float16)(y[ni][r] + Dh * xval);
    }

  f32x4 t4[4];
#pragma unroll
  for (int q = 0; q < 4; ++q) t4[q] = (f32x4){0.f, 0.f, 0.f, 0.f};
#pragma unroll
  for (int ni = 0; ni < 4; ++ni)
#pragma unroll
    for (int ks = 0; ks < 2; ++ks)
      t4[ni] = __builtin_amdgcn_mfma_f32_16x16x32_f16(
          *(const f16x8*)&sBT[i0 + r16][ks * 32 + quad * 8],
          *(const f16x8*)&sXT[ni * 16 + r16][ks * 32 + quad * 8], t4[ni], 0, 0, 0);
  _Float16* sp = Sbuf + (size_t)gidx * (DS * P_);
#pragma unroll
  for (int ni = 0; ni < 4; ++ni)
#pragma unroll
    for (int r = 0; r < 4; ++r)
      sp[(irow + r) * P_ + ni * 16 + r16] = (_Float16)t4[ni][r];
}

// ---------------- sequential inter-chunk recurrence (in-place, fp16 storage) ----------------
// 16 segments (768 waves) + group-of-8 double-buffered prefetch (proven r5).
__global__ __launch_bounds__(64)
void k_chunkscan(_Float16* __restrict__ Sbuf, const float* __restrict__ cumA)
{
  const int seg = blockIdx.x, h = blockIdx.y, bz = blockIdx.z;
  const int bh = bz * H_ + h;
  __shared__ float dec[NC];
  const int tid = threadIdx.x;
  dec[tid] = expf(cumA[((size_t)(bh * NC + tid)) * Q_ + (Q_ - 1)]);
  __syncthreads();
  _Float16* base = Sbuf + (size_t)bh * NC * (DS * P_) + (size_t)seg * 256 + (size_t)tid * 4;
  float s[4] = {0.f, 0.f, 0.f, 0.f};
  f16x4 bA[8], bB[8];
#pragma unroll
  for (int j = 0; j < 8; ++j) bA[j] = *(const f16x4*)(base + (size_t)j * (DS * P_));
#pragma unroll
  for (int g = 0; g < 8; ++g) {
    if (g + 1 < 8) {                       // prefetch next group into the other buffer
#pragma unroll
      for (int j = 0; j < 8; ++j) {
        f16x4 v = *(const f16x4*)(base + (size_t)((g + 1) * 8 + j) * (DS * P_));
        if (g & 1) bA[j] = v; else bB[j] = v;   // compile-time after full unroll
      }
    }
#pragma unroll
    for (int j = 0; j < 8; ++j) {
      const int c = g * 8 + j;
      f16x4 cur = (g & 1) ? bB[j] : bA[j];
      f16x4 sto;
#pragma unroll
      for (int e = 0; e < 4; ++e) sto[e] = (_Float16)s[e];
      *(f16x4*)(base + (size_t)c * (DS * P_)) = sto;       // state BEFORE chunk c
      const float d = dec[c];
#pragma unroll
      for (int e = 0; e < 4; ++e) s[e] = s[e] * d + (float)cur[e];
    }
  }
}

// ---------------- inter-chunk correction (ytot fp16 RMW); D*x lives in k_intra ----------------
__global__ __launch_bounds__(256)
void k_inter(const float* __restrict__ Cm, const float* __restrict__ cumA,
             const _Float16* __restrict__ Sbuf, _Float16* __restrict__ ytot)
{
  const int c = blockIdx.x, h = blockIdx.y, bz = blockIdx.z;
  const int gidx = (bz * H_ + h) * NC + c;
  __shared__ float sS[DS][SP];
  __shared__ float sC[Q_][SP];
  __shared__ float scum[Q_];
  const int tid = threadIdx.x;
  const int jr = tid >> 2, blk = (tid & 3) * 16;
  const int rowbase = bz * L_ + c * Q_;
  {
    const _Float16* ssrc = Sbuf + (size_t)gidx * (DS * P_) + jr * P_ + blk;
    f16x8 sv0 = *(const f16x8*)ssrc;
    f16x8 sv1 = *(const f16x8*)(ssrc + 8);
    const float* csrc = Cm + (size_t)(rowbase + jr) * DS + blk;
#pragma unroll
    for (int o = 0; o < 8; ++o) {
      sS[jr][blk + o]     = (float)sv0[o];
      sS[jr][blk + 8 + o] = (float)sv1[o];
    }
#pragma unroll
    for (int q = 0; q < 4; ++q)
      *(f32x4*)&sC[jr][blk + q * 4] = *(const f32x4*)(csrc + q * 4);
    if (tid < Q_) scum[tid] = cumA[(size_t)gidx * Q_ + tid];
  }
  __syncthreads();
  const int i = jr;
  f32x4 acc[4];
#pragma unroll
  for (int q = 0; q < 4; ++q) acc[q] = (f32x4){0.f, 0.f, 0.f, 0.f};
  for (int n = 0; n < DS; ++n) {
    float cv = sC[i][n];
#pragma unroll
    for (int q = 0; q < 4; ++q) acc[q] += cv * *(const f32x4*)&sS[n][blk + q * 4];
  }
  const float e = expf(scum[i]);
  _Float16* yt = ytot + (size_t)(rowbase + i) * DI + h * P_ + blk;
  f16x8 y0 = *(const f16x8*)yt;
  f16x8 y1 = *(const f16x8*)(yt + 8);
#pragma unroll
  for (int o = 0; o < 16; ++o) {
    float cur = (float)((o < 8) ? y0[o] : y1[o - 8]);
    cur += e * acc[o >> 2][o & 3];
    if (o < 8) y0[o] = (_Float16)cur; else y1[o - 8] = (_Float16)cur;
  }
  *(f16x8*)yt = y0;
  *(f16x8*)(yt + 8) = y1;
}

// ---------------- gate (silu(z)) + RMSNorm + cast bf16 ----------------
__global__ __launch_bounds__(192)
void k_rms(const unsigned short* __restrict__ z, const _Float16* __restrict__ ytot,
           const float* __restrict__ norm_w, unsigned short* __restrict__ ynorm)
{
  const int row = blockIdx.x, tid = threadIdx.x;
  const int e0 = tid * 8;
  us8 zv = *(const us8*)(z + (size_t)row * DI + e0);
  f16x8 yv = *(const f16x8*)(ytot + (size_t)row * DI + e0);
  float g[8];
  float ss = 0.f;
#pragma unroll
  for (int q = 0; q < 8; ++q) {
    g[q] = (float)yv[q] * siluf(bf2f(zv[q]));
    ss += g[q] * g[q];
  }
#pragma unroll
  for (int off = 32; off > 0; off >>= 1) ss += __shfl_down(ss, off);
  __shared__ float wsum[3];
  __shared__ float sscale;
  if ((tid & 63) == 0) wsum[tid >> 6] = ss;
  __syncthreads();
  if (tid == 0) sscale = rsqrtf((wsum[0] + wsum[1] + wsum[2]) * (1.f / DI) + 1e-5f);
  __syncthreads();
  const float sc = sscale;
  us8 o;
#pragma unroll
  for (int q = 0; q < 8; ++q) o[q] = f2bf(g[q] * sc * norm_w[e0 + q]);
  *(us8*)(ynorm + (size_t)row * DI + e0) = o;
}

extern "C" void kernel_launch(void* const* d_in, const int* in_sizes, int n_in,
                              void* d_out, int out_size, void* d_ws, size_t ws_size,
                              hipStream_t stream)
{
  (void)in_sizes; (void)n_in; (void)out_size;
  const float* x       = (const float*)d_in[0];
  const float* W_in    = (const float*)d_in[1];
  const float* conv_w  = (const float*)d_in[2];
  const float* conv_b  = (const float*)d_in[3];
  const float* dt_bias = (const float*)d_in[4];
  const float* A_log   = (const float*)d_in[5];
  const float* Dp      = (const float*)d_in[6];
  const float* norm_w  = (const float*)d_in[7];
  const float* W_out   = (const float*)d_in[8];
  float* out = (float*)d_out;

  // ---- batches per pass: footprint(nb) = nb*L_*16320 + 7,385,088 ----
  const int nb = ((size_t)2 * L_ * 16320 + 7385088 <= ws_size) ? 2 : 1;
  const int rows = nb * L_;

  // ---- workspace layout (per-pass buffers) ----
  char* ws = (char*)d_ws;
  unsigned short* zseg = (unsigned short*)ws;  ws += (size_t)rows * DI * 2;   // bf16 z
  unsigned short* xbc  = (unsigned short*)ws;  ws += (size_t)rows * CD * 2;   // bf16 xBC
  _Float16* xs   = (_Float16*)ws;  ws += (size_t)rows * DI * 2;               // (ynorm home)
  _Float16* ytot = (_Float16*)ws;  ws += (size_t)rows * DI * 2;               // fp16 y
  float* Bm   = (float*)ws;  ws += (size_t)rows * DS * 4;
  float* Cm   = (float*)ws;  ws += (size_t)rows * DS * 4;
  float* dtv  = (float*)ws;  ws += (size_t)rows * H_ * 4;
  float* cumA = (float*)ws;  ws += (size_t)rows * H_ * 4;
  _Float16* Sbuf = (_Float16*)ws;  ws += (size_t)rows * 3072;  // nb*H_*NC*DS*P_*2
  unsigned short* WinT  = (unsigned short*)ws; ws += (size_t)NPJ * DM * 2;
  unsigned short* WoutT = (unsigned short*)ws; ws += (size_t)DM * DI * 2;
  float* WdtT   = (float*)ws;  ws += (size_t)H_ * DM * 4;
  unsigned short* xb    = (unsigned short*)Sbuf;     // overlay: Sbuf dead until k_intra
  unsigned short* ynorm = (unsigned short*)xs;       // overlay: xs slot free (conv fused)

  k_transpose_cast<<<dim3(24, (NPJ + 31) / 32), 256, 0, stream>>>(W_in, WinT, DM, NPJ);
  k_transpose_cast<<<dim3(48, 24), 256, 0, stream>>>(W_out, WoutT, DI, DM);
  k_wdtT<<<(H_ * DM + 255) / 256, 256, 0, stream>>>(W_in, WdtT);

  for (int b0 = 0; b0 < B_; b0 += nb) {
    const float* xp = x + (size_t)b0 * L_ * DM;

    k_dt2<<<rows / 16, 384, 0, stream>>>(xp, WdtT, dt_bias, dtv, xb);
    // in-proj: 256x128 block (512 thr), wave tile 64x64 (r6 win: 50.9us)
    k_gemm_t<256, 128, 64, 64, true><<<dim3(rows / 256, N1 / 128), 512, 0, stream>>>(
        xb, WinT, zseg, DI, DI, xbc, CD, DM);
    // slim conv: only B/C channels (DI part fused into k_intra)
    k_conv2<<<rows / CROWS, 128, 0, stream>>>(xbc, conv_w, conv_b, Bm, Cm);
    k_intra<<<dim3(NC, H_, nb), 256, 0, stream>>>(xbc, conv_w, conv_b, Bm, Cm, dtv,
                                                  A_log, Dp, cumA, ytot, Sbuf);
    k_chunkscan<<<dim3(16, H_, nb), 64, 0, stream>>>(Sbuf, cumA);
    k_inter<<<dim3(NC, H_, nb), 256, 0, stream>>>(Cm, cumA, Sbuf, ytot);
    k_rms<<<rows, 192, 0, stream>>>(zseg, ytot, norm_w, ynorm);
    // out-proj: r0-proven <128,64,64,32> -> 768 blocks = 3 even rounds on 256 CUs
    k_gemm_t<128, 64, 64, 32, false><<<dim3(rows / 128, DM / 64), 256, 0, stream>>>(
        ynorm, WoutT, out + (size_t)b0 * L_ * DM, DM, DM, out + (size_t)b0 * L_ * DM, DM, DI);
  }
}

// Round 11
// 301.164 us; speedup vs baseline: 1.0337x; 1.0337x over previous
//
#include <hip/hip_runtime.h>

// ---- problem constants ----
#define B_   2
#define L_   4096
#define DM   768
#define DI   1536     // D_INNER
#define DS   64       // D_STATE
#define H_   24       // NHEADS
#define P_   64       // HEADDIM
#define CD   1664     // CONV_DIM
#define NPJ  3224     // D_IN_PROJ
#define N1   3200     // GEMM1 useful cols (z + xBC; dt cols done exactly in k_dt2)
#define Q_   64       // chunk length
#define NC   64       // chunks per batch
#define SP   76       // LDS row stride (floats) for k_inter tiles
#define HS   72       // fp16 LDS row stride (halves): <=2-way conflicts
#define WDS  772      // k_dt2 LDS W stride (772%32=4 -> 3-way max bank aliasing)
#define CROWS 16      // conv rows per thread

typedef short          bf16x8 __attribute__((ext_vector_type(8)));
typedef _Float16       f16x8  __attribute__((ext_vector_type(8)));
typedef _Float16       f16x4  __attribute__((ext_vector_type(4)));
typedef unsigned short us8    __attribute__((ext_vector_type(8)));
typedef unsigned short us4    __attribute__((ext_vector_type(4)));
typedef float          f32x4  __attribute__((ext_vector_type(4)));

__device__ __forceinline__ unsigned short f2bf(float f) {
  unsigned u = __float_as_uint(f);
  u += 0x7fffu + ((u >> 16) & 1u);   // RNE
  return (unsigned short)(u >> 16);
}
__device__ __forceinline__ float bf2f(unsigned short u) {
  return __uint_as_float(((unsigned)u) << 16);
}
__device__ __forceinline__ float siluf(float x) { return x / (1.f + expf(-x)); }
__device__ __forceinline__ float softplusf(float x) { return (x > 20.f) ? x : log1pf(expf(x)); }

// async global->LDS, 16B per lane; LDS dest = uniform base + lane*16
__device__ __forceinline__ void gload16(const unsigned short* g, unsigned short* l) {
  __builtin_amdgcn_global_load_lds(
      (const __attribute__((address_space(1))) void*)g,
      (__attribute__((address_space(3))) void*)l, 16, 0, 0);
}

// ---------------- transpose + cast (R x C fp32) -> (C x R bf16) ----------------
__global__ __launch_bounds__(256)
void k_transpose_cast(const float* __restrict__ src, unsigned short* __restrict__ dst,
                      int R, int C)
{
  __shared__ float tile[32][33];
  const int tx = threadIdx.x & 31, ty = threadIdx.x >> 5;
  const int r0 = blockIdx.x * 32, c0 = blockIdx.y * 32;
#pragma unroll
  for (int r = 0; r < 4; ++r) {
    int rr = r0 + ty + r * 8, cc = c0 + tx;
    if (rr < R && cc < C) tile[ty + r * 8][tx] = src[(size_t)rr * C + cc];
  }
  __syncthreads();
#pragma unroll
  for (int r = 0; r < 4; ++r) {
    int orow = c0 + ty + r * 8, ocol = r0 + tx;
    if (orow < C && ocol < R) dst[(size_t)orow * R + ocol] = f2bf(tile[tx][ty + r * 8]);
  }
}

// ---------------- gather dt columns of W_in -> contiguous fp32 WdtT[24][768] ----------------
__global__ void k_wdtT(const float* __restrict__ W_in, float* __restrict__ WdtT)
{
  const int idx = blockIdx.x * 256 + threadIdx.x;
  if (idx >= H_ * DM) return;
  const int k = idx / H_, h = idx % H_;
  WdtT[(size_t)h * DM + k] = W_in[(size_t)k * NPJ + N1 + h];
}

// ---------------- bf16 MFMA GEMM, BK=64, XOR-swizzled LDS (conflict-free) ----------------
// in-proj <256,128,64,64>@512thr (r6: 50.9us); out-proj <128,64,64,32>@256thr
// (768 blocks = 3 even rounds). r6 lesson: tiles must divide the grid evenly.
template<int BM, int BN, int WM, int WN, bool OUT_BF16>
__global__ __launch_bounds__((BM / WM) * (BN / WN) * 64)
void k_gemm_t(const unsigned short* __restrict__ A, const unsigned short* __restrict__ Bt,
              void* __restrict__ C0v, int ld0, int ncol0,
              void* __restrict__ C1v, int ld1, int K)
{
  constexpr int MI = WM / 16, NI = WN / 16;
  constexpr int WAVES_N = BN / WN;
  constexpr int T  = (BM / WM) * (BN / WN) * 64;  // threads
  constexpr int RG = T / 8;                       // rows per gload band (T*16B / 128B row)
  constexpr int RA = BM / RG, RB = BN / RG;
  const int m0 = blockIdx.x * BM, n0 = blockIdx.y * BN;
  __shared__ unsigned short As[BM][64];
  __shared__ unsigned short Bs[BN][64];
  const int tid  = threadIdx.x;
  const int wave = tid >> 6, lane = tid & 63;
  const int quad = lane >> 4, r16 = lane & 15;
  const int wm = (wave / WAVES_N) * WM, wn = (wave % WAVES_N) * WN;

  const int lr8 = lane >> 3;                                // 0..7 row-in-band
  const int csw = ((lane & 7) ^ lr8) * 8;                   // swizzled source col (shorts)
  const unsigned short* gA = A  + (size_t)(m0 + wave * 8 + lr8) * K + csw;
  const unsigned short* gB = Bt + (size_t)(n0 + wave * 8 + lr8) * K + csw;
  unsigned short* lA = &As[wave * 8][0] + (size_t)lane * 8; // +lane*16B
  unsigned short* lB = &Bs[wave * 8][0] + (size_t)lane * 8;

  f32x4 acc[MI][NI];
#pragma unroll
  for (int mi = 0; mi < MI; ++mi)
#pragma unroll
    for (int ni = 0; ni < NI; ++ni) acc[mi][ni] = (f32x4){0.f, 0.f, 0.f, 0.f};

  for (int k0 = 0; k0 < K; k0 += 64) {
#pragma unroll
    for (int r = 0; r < RA; ++r)
      gload16(gA + (size_t)(r * RG) * K + k0, lA + (size_t)r * RG * 64);
#pragma unroll
    for (int r = 0; r < RB; ++r)
      gload16(gB + (size_t)(r * RG) * K + k0, lB + (size_t)r * RG * 64);
    __syncthreads();
    bf16x8 af[MI][2], bfr[NI][2];
#pragma unroll
    for (int mi = 0; mi < MI; ++mi)
#pragma unroll
      for (int ks = 0; ks < 2; ++ks)
        af[mi][ks] = *(const bf16x8*)&As[wm + mi * 16 + r16][((quad + ks * 4) ^ (r16 & 7)) * 8];
#pragma unroll
    for (int ni = 0; ni < NI; ++ni)
#pragma unroll
      for (int ks = 0; ks < 2; ++ks)
        bfr[ni][ks] = *(const bf16x8*)&Bs[wn + ni * 16 + r16][((quad + ks * 4) ^ (r16 & 7)) * 8];
#pragma unroll
    for (int mi = 0; mi < MI; ++mi)
#pragma unroll
      for (int ni = 0; ni < NI; ++ni)
#pragma unroll
        for (int ks = 0; ks < 2; ++ks)
          acc[mi][ni] = __builtin_amdgcn_mfma_f32_16x16x32_bf16(
              af[mi][ks], bfr[ni][ks], acc[mi][ni], 0, 0, 0);
    __syncthreads();
  }
#pragma unroll
  for (int mi = 0; mi < MI; ++mi)
#pragma unroll
    for (int ni = 0; ni < NI; ++ni) {
      int col = n0 + wn + ni * 16 + r16;
      void* dst; int ld, c;
      if (col < ncol0) { dst = C0v; ld = ld0; c = col; }
      else             { dst = C1v; ld = ld1; c = col - ncol0; }
#pragma unroll
      for (int r = 0; r < 4; ++r) {
        int row = m0 + wm + mi * 16 + quad * 4 + r;
        if (OUT_BF16) ((unsigned short*)dst)[(size_t)row * ld + c] = f2bf(acc[mi][ni][r]);
        else          ((float*)dst)[(size_t)row * ld + c] = acc[mi][ni][r];
      }
    }
}

// ---------------- slim conv: only B/C channels [DI, DI+128) ----------------
__global__ __launch_bounds__(128)
void k_conv2(const unsigned short* __restrict__ xbc, const float* __restrict__ cw,
             const float* __restrict__ cb, float* __restrict__ Bm, float* __restrict__ Cm)
{
  const int ch = DI + threadIdx.x;                // 128 threads: DI..DI+127
  const int r0 = blockIdx.x * CROWS;
  const float w0 = cw[ch * 4], w1 = cw[ch * 4 + 1], w2 = cw[ch * 4 + 2], w3 = cw[ch * 4 + 3];
  const float bias = cb[ch];
  float a, b, c;
  if ((r0 & (L_ - 1)) == 0) {                 // batch start: zero history
    a = 0.f; b = 0.f; c = 0.f;
  } else {
    a = bf2f(xbc[(size_t)(r0 - 3) * CD + ch]);
    b = bf2f(xbc[(size_t)(r0 - 2) * CD + ch]);
    c = bf2f(xbc[(size_t)(r0 - 1) * CD + ch]);
  }
#pragma unroll
  for (int i = 0; i < CROWS; ++i) {
    const int lr = r0 + i;
    float d = bf2f(xbc[(size_t)lr * CD + ch]);
    float v = siluf(bias + a * w0 + b * w1 + c * w2 + d * w3);
    a = b; b = c; c = d;
    if (threadIdx.x < DS) Bm[(size_t)lr * DS + threadIdx.x] = v;
    else                  Cm[(size_t)lr * DS + (threadIdx.x - DS)] = v;
  }
}

// ---------------- exact fp32 dt, v6: wave-uniform K-split x2 ----------------
// History: v5 (r9, ~44us) = 12 waves/CU, 768-FMA serial chain. v3's K-split (r8)
// failed because lanes in one wave mixed rows AND K-quarters -> scattered loads.
// v6 splits K at the BLOCK level: 768 threads, threads >=384 take k in [384,768).
// Every wave keeps v5's exact broadcast load pattern (wave-uniform K-half).
// Chain 768->384 FMA; 2 blk/CU x 12 waves = 24 waves/CU; staging over 2x threads.
// Partials combined via 1.6KB LDS (+1 barrier). fp32 reassociation only (r8
// already passed with K-split reassociation).
__global__ __launch_bounds__(768)
void k_dt2(const float* __restrict__ x, const float* __restrict__ WdtT,
           const float* __restrict__ dt_bias, float* __restrict__ dtv,
           unsigned short* __restrict__ xb)
{
  __shared__ float sW[H_][WDS];
  __shared__ float part[16][25];
  const int tid = threadIdx.x;
  for (int i = tid; i < H_ * DM; i += 768)
    sW[i / DM][i % DM] = WdtT[i];
  const int half = tid >> 9 | ((tid >> 8) & (tid >> 7) & 1);   // tid >= 384
  const int t2 = tid - half * 384;
  const int h = t2 % H_, rloc = t2 / H_;       // rloc 0..15
  const int row0 = blockIdx.x * 16;
  const int lrow = row0 + rloc;
  const float* xr = x + (size_t)lrow * DM + half * 384;
  const float* wr = &sW[h][half * 384];
  __syncthreads();
  float acc = 0.f;
#pragma unroll 8
  for (int k = 0; k < 384; k += 4) {
    f32x4 xv = *(const f32x4*)(xr + k);
    f32x4 wv = *(const f32x4*)(wr + k);
    acc += xv[0] * wv[0] + xv[1] * wv[1] + xv[2] * wv[2] + xv[3] * wv[3];
  }
  if (half) part[rloc][h] = acc;
  __syncthreads();
  if (!half) {
    acc += part[rloc][h];
    dtv[(size_t)lrow * H_ + h] = softplusf(acc + dt_bias[h]);
  }
  // fused x->bf16 cast: 16 rows x 768 cols / 768 thr = 16 floats each (L1-hot)
  const int crow = tid / 48, ccol = (tid % 48) * 16;
  const float* xi = x + (size_t)(row0 + crow) * DM + ccol;
  unsigned short* xo = xb + (size_t)(row0 + crow) * DM + ccol;
#pragma unroll
  for (int j = 0; j < 16; j += 8) {
    f32x4 a = *(const f32x4*)(xi + j);
    f32x4 b = *(const f32x4*)(xi + j + 4);
    us8 o;
#pragma unroll
    for (int e = 0; e < 4; ++e) { o[e] = f2bf(a[e]); o[e + 4] = f2bf(b[e]); }
    *(us8*)(xo + j) = o;
  }
}

// ---------------- intra-chunk via fp16 MFMA; ytot/Sbuf stored fp16 ----------------
// Depthwise conv for the DI channels FUSED into the x-stage (reads xbc directly).
// k_cum fused (wave-0 scan); D*x fused into the y-store.
__global__ __launch_bounds__(256)
void k_intra(const unsigned short* __restrict__ xbc, const float* __restrict__ cw,
             const float* __restrict__ cb, const float* __restrict__ Bm,
             const float* __restrict__ Cm, const float* __restrict__ dtv,
             const float* __restrict__ A_log, const float* __restrict__ Dp,
             float* __restrict__ cumA, _Float16* __restrict__ ytot,
             _Float16* __restrict__ Sbuf)
{
  const int c = blockIdx.x, h = blockIdx.y, bz = blockIdx.z;
  const int gidx = (bz * H_ + h) * NC + c;
  __shared__ _Float16 sCW[Q_][HS];   // C, then W
  __shared__ _Float16 sB [Q_][HS];
  __shared__ _Float16 sBT[Q_][HS];   // (coef_j * B[j][n]) transposed -> [n][j]
  __shared__ _Float16 sXT[Q_][HS];   // X transposed -> [p][j]
  __shared__ float scum[Q_], sdt[Q_];
  __shared__ float scw[4][Q_];       // conv weights for this head's 64 channels
  __shared__ float scb[Q_];          // conv bias
  const int tid = threadIdx.x;
  const int rowbase = bz * L_ + c * Q_;
  const int ch0 = h * P_;            // head's channel base within xbc

  {
    const int j = tid >> 2, s16 = (tid & 3) * 16;
    if (tid < Q_) {                       // wave 0 only: scan dt -> scum, emit cumA
      const float dtval = dtv[(size_t)(rowbase + tid) * H_ + h];
      sdt[tid] = dtval;
      const float A = -expf(A_log[h]);
      float v = dtval;
#pragma unroll
      for (int off = 1; off < 64; off <<= 1) {
        float o = __shfl_up(v, off, 64);
        if (tid >= off) v += o;
      }
      v *= A;
      scum[tid] = v;
      cumA[(size_t)gidx * Q_ + tid] = v;
    }
    // stage conv weights/bias for channels ch0..ch0+63 (coalesced: cw[ch0*4+tid])
    scw[tid & 3][tid >> 2] = cw[(size_t)ch0 * 4 + tid];
    if (tid < Q_) scb[tid] = cb[ch0 + tid];
    // xbc loads for conv: rows rowbase+j-3..rowbase+j, channels ch0+s16..+16
    us8 xr[4][2];
    const int rbz = bz * L_;
#pragma unroll
    for (int d = 0; d < 4; ++d) {
      const int rr = rowbase + j - 3 + d;
      const int rc = (rr < rbz) ? rbz : rr;        // clamp (loads valid ws memory)
      const unsigned short* src = xbc + (size_t)rc * CD + ch0 + s16;
      xr[d][0] = *(const us8*)src;
      xr[d][1] = *(const us8*)(src + 8);
      if (rr < rbz) {                               // zero history at batch start
        us8 z8 = {0, 0, 0, 0, 0, 0, 0, 0};
        xr[d][0] = z8; xr[d][1] = z8;
      }
    }
    f32x4 bv[4], cv[4];
    const float* bsrc = Bm + (size_t)(rowbase + j) * DS + s16;
    const float* csrc = Cm + (size_t)(rowbase + j) * DS + s16;
#pragma unroll
    for (int q = 0; q < 4; ++q) {
      bv[q] = *(const f32x4*)(bsrc + q * 4);
      cv[q] = *(const f32x4*)(csrc + q * 4);
    }
    __syncthreads();                                // covers scum, scw, scb
    const float coef = expf(scum[Q_ - 1] - scum[j]) * sdt[j];
    union { f16x8 v; _Float16 e[8]; } pc[2], pb[2];
#pragma unroll
    for (int q = 0; q < 4; ++q)
#pragma unroll
      for (int e = 0; e < 4; ++e) {
        int o = q * 4 + e;
        const int cc = s16 + o;
        pc[o >> 3].e[o & 7] = (_Float16)cv[q][e];
        pb[o >> 3].e[o & 7] = (_Float16)bv[q][e];
        sBT[cc][j] = (_Float16)(bv[q][e] * coef);
        // fused depthwise conv(4) + silu for channel ch0+cc, row rowbase+j
        float a0 = bf2f(xr[0][o >> 3][o & 7]);
        float a1 = bf2f(xr[1][o >> 3][o & 7]);
        float a2 = bf2f(xr[2][o >> 3][o & 7]);
        float a3 = bf2f(xr[3][o >> 3][o & 7]);
        float v = scb[cc] + a0 * scw[0][cc] + a1 * scw[1][cc]
                          + a2 * scw[2][cc] + a3 * scw[3][cc];
        sXT[cc][j] = (_Float16)siluf(v);
      }
    *(f16x8*)&sCW[j][s16]     = pc[0].v;
    *(f16x8*)&sCW[j][s16 + 8] = pc[1].v;
    *(f16x8*)&sB [j][s16]     = pb[0].v;
    *(f16x8*)&sB [j][s16 + 8] = pb[1].v;
  }
  __syncthreads();

  const int wave = tid >> 6, lane = tid & 63;
  const int quad = lane >> 4, r16 = lane & 15;
  const int i0 = wave * 16;
  const int irow = i0 + quad * 4;

  f32x4 g[4];
#pragma unroll
  for (int q = 0; q < 4; ++q) g[q] = (f32x4){0.f, 0.f, 0.f, 0.f};
#pragma unroll
  for (int ni = 0; ni < 4; ++ni) {
    if (ni <= wave) {
#pragma unroll
      for (int ks = 0; ks < 2; ++ks)
        g[ni] = __builtin_amdgcn_mfma_f32_16x16x32_f16(
            *(const f16x8*)&sCW[i0 + r16][ks * 32 + quad * 8],
            *(const f16x8*)&sB [ni * 16 + r16][ks * 32 + quad * 8], g[ni], 0, 0, 0);
    }
  }
  float wv[4][4];
#pragma unroll
  for (int ni = 0; ni < 4; ++ni)
#pragma unroll
    for (int r = 0; r < 4; ++r) {
      int i = irow + r, jcol = ni * 16 + r16;
      float v = 0.f;
      if (ni <= wave && jcol <= i)
        v = g[ni][r] * expf(scum[i] - scum[jcol]) * sdt[jcol];
      wv[ni][r] = v;
    }
  __syncthreads();
#pragma unroll
  for (int ni = 0; ni < 4; ++ni)
#pragma unroll
    for (int r = 0; r < 4; ++r)
      sCW[irow + r][ni * 16 + r16] = (_Float16)wv[ni][r];
  __syncthreads();

  const float Dh = Dp[h];
  f32x4 y[4];
#pragma unroll
  for (int q = 0; q < 4; ++q) y[q] = (f32x4){0.f, 0.f, 0.f, 0.f};
#pragma unroll
  for (int ni = 0; ni < 4; ++ni)
#pragma unroll
    for (int ks = 0; ks < 2; ++ks) {
      if (ks == 0 || wave >= 2)
        y[ni] = __builtin_amdgcn_mfma_f32_16x16x32_f16(
            *(const f16x8*)&sCW[i0 + r16][ks * 32 + quad * 8],
            *(const f16x8*)&sXT[ni * 16 + r16][ks * 32 + quad * 8], y[ni], 0, 0, 0);
    }
#pragma unroll
  for (int ni = 0; ni < 4; ++ni)
#pragma unroll
    for (int r = 0; r < 4; ++r) {
      const float xval = (float)sXT[ni * 16 + r16][irow + r];   // X[irow+r][ni*16+r16]
      ytot[(size_t)(rowbase + irow + r) * DI + h * P_ + ni * 16 + r16] =
          (_Float16)(y[ni][r] + Dh * xval);
    }

  f32x4 t4[4];
#pragma unroll
  for (int q = 0; q < 4; ++q) t4[q] = (f32x4){0.f, 0.f, 0.f, 0.f};
#pragma unroll
  for (int ni = 0; ni < 4; ++ni)
#pragma unroll
    for (int ks = 0; ks < 2; ++ks)
      t4[ni] = __builtin_amdgcn_mfma_f32_16x16x32_f16(
          *(const f16x8*)&sBT[i0 + r16][ks * 32 + quad * 8],
          *(const f16x8*)&sXT[ni * 16 + r16][ks * 32 + quad * 8], t4[ni], 0, 0, 0);
  _Float16* sp = Sbuf + (size_t)gidx * (DS * P_);
#pragma unroll
  for (int ni = 0; ni < 4; ++ni)
#pragma unroll
    for (int r = 0; r < 4; ++r)
      sp[(irow + r) * P_ + ni * 16 + r16] = (_Float16)t4[ni][r];
}

// ---------------- sequential inter-chunk recurrence (in-place, fp16 storage) ----------------
// 16 segments (768 waves) + group-of-8 double-buffered prefetch (proven r5).
__global__ __launch_bounds__(64)
void k_chunkscan(_Float16* __restrict__ Sbuf, const float* __restrict__ cumA)
{
  const int seg = blockIdx.x, h = blockIdx.y, bz = blockIdx.z;
  const int bh = bz * H_ + h;
  __shared__ float dec[NC];
  const int tid = threadIdx.x;
  dec[tid] = expf(cumA[((size_t)(bh * NC + tid)) * Q_ + (Q_ - 1)]);
  __syncthreads();
  _Float16* base = Sbuf + (size_t)bh * NC * (DS * P_) + (size_t)seg * 256 + (size_t)tid * 4;
  float s[4] = {0.f, 0.f, 0.f, 0.f};
  f16x4 bA[8], bB[8];
#pragma unroll
  for (int j = 0; j < 8; ++j) bA[j] = *(const f16x4*)(base + (size_t)j * (DS * P_));
#pragma unroll
  for (int g = 0; g < 8; ++g) {
    if (g + 1 < 8) {                       // prefetch next group into the other buffer
#pragma unroll
      for (int j = 0; j < 8; ++j) {
        f16x4 v = *(const f16x4*)(base + (size_t)((g + 1) * 8 + j) * (DS * P_));
        if (g & 1) bA[j] = v; else bB[j] = v;   // compile-time after full unroll
      }
    }
#pragma unroll
    for (int j = 0; j < 8; ++j) {
      const int c = g * 8 + j;
      f16x4 cur = (g & 1) ? bB[j] : bA[j];
      f16x4 sto;
#pragma unroll
      for (int e = 0; e < 4; ++e) sto[e] = (_Float16)s[e];
      *(f16x4*)(base + (size_t)c * (DS * P_)) = sto;       // state BEFORE chunk c
      const float d = dec[c];
#pragma unroll
      for (int e = 0; e < 4; ++e) s[e] = s[e] * d + (float)cur[e];
    }
  }
}

// ---------------- inter-chunk correction (ytot fp16 RMW); D*x lives in k_intra ----------------
__global__ __launch_bounds__(256)
void k_inter(const float* __restrict__ Cm, const float* __restrict__ cumA,
             const _Float16* __restrict__ Sbuf, _Float16* __restrict__ ytot)
{
  const int c = blockIdx.x, h = blockIdx.y, bz = blockIdx.z;
  const int gidx = (bz * H_ + h) * NC + c;
  __shared__ float sS[DS][SP];
  __shared__ float sC[Q_][SP];
  __shared__ float scum[Q_];
  const int tid = threadIdx.x;
  const int jr = tid >> 2, blk = (tid & 3) * 16;
  const int rowbase = bz * L_ + c * Q_;
  {
    const _Float16* ssrc = Sbuf + (size_t)gidx * (DS * P_) + jr * P_ + blk;
    f16x8 sv0 = *(const f16x8*)ssrc;
    f16x8 sv1 = *(const f16x8*)(ssrc + 8);
    const float* csrc = Cm + (size_t)(rowbase + jr) * DS + blk;
#pragma unroll
    for (int o = 0; o < 8; ++o) {
      sS[jr][blk + o]     = (float)sv0[o];
      sS[jr][blk + 8 + o] = (float)sv1[o];
    }
#pragma unroll
    for (int q = 0; q < 4; ++q)
      *(f32x4*)&sC[jr][blk + q * 4] = *(const f32x4*)(csrc + q * 4);
    if (tid < Q_) scum[tid] = cumA[(size_t)gidx * Q_ + tid];
  }
  __syncthreads();
  const int i = jr;
  f32x4 acc[4];
#pragma unroll
  for (int q = 0; q < 4; ++q) acc[q] = (f32x4){0.f, 0.f, 0.f, 0.f};
  for (int n = 0; n < DS; ++n) {
    float cv = sC[i][n];
#pragma unroll
    for (int q = 0; q < 4; ++q) acc[q] += cv * *(const f32x4*)&sS[n][blk + q * 4];
  }
  const float e = expf(scum[i]);
  _Float16* yt = ytot + (size_t)(rowbase + i) * DI + h * P_ + blk;
  f16x8 y0 = *(const f16x8*)yt;
  f16x8 y1 = *(const f16x8*)(yt + 8);
#pragma unroll
  for (int o = 0; o < 16; ++o) {
    float cur = (float)((o < 8) ? y0[o] : y1[o - 8]);
    cur += e * acc[o >> 2][o & 3];
    if (o < 8) y0[o] = (_Float16)cur; else y1[o - 8] = (_Float16)cur;
  }
  *(f16x8*)yt = y0;
  *(f16x8*)(yt + 8) = y1;
}

// ---------------- gate (silu(z)) + RMSNorm + cast bf16 ----------------
__global__ __launch_bounds__(192)
void k_rms(const unsigned short* __restrict__ z, const _Float16* __restrict__ ytot,
           const float* __restrict__ norm_w, unsigned short* __restrict__ ynorm)
{
  const int row = blockIdx.x, tid = threadIdx.x;
  const int e0 = tid * 8;
  us8 zv = *(const us8*)(z + (size_t)row * DI + e0);
  f16x8 yv = *(const f16x8*)(ytot + (size_t)row * DI + e0);
  float g[8];
  float ss = 0.f;
#pragma unroll
  for (int q = 0; q < 8; ++q) {
    g[q] = (float)yv[q] * siluf(bf2f(zv[q]));
    ss += g[q] * g[q];
  }
#pragma unroll
  for (int off = 32; off > 0; off >>= 1) ss += __shfl_down(ss, off);
  __shared__ float wsum[3];
  __shared__ float sscale;
  if ((tid & 63) == 0) wsum[tid >> 6] = ss;
  __syncthreads();
  if (tid == 0) sscale = rsqrtf((wsum[0] + wsum[1] + wsum[2]) * (1.f / DI) + 1e-5f);
  __syncthreads();
  const float sc = sscale;
  us8 o;
#pragma unroll
  for (int q = 0; q < 8; ++q) o[q] = f2bf(g[q] * sc * norm_w[e0 + q]);
  *(us8*)(ynorm + (size_t)row * DI + e0) = o;
}

extern "C" void kernel_launch(void* const* d_in, const int* in_sizes, int n_in,
                              void* d_out, int out_size, void* d_ws, size_t ws_size,
                              hipStream_t stream)
{
  (void)in_sizes; (void)n_in; (void)out_size;
  const float* x       = (const float*)d_in[0];
  const float* W_in    = (const float*)d_in[1];
  const float* conv_w  = (const float*)d_in[2];
  const float* conv_b  = (const float*)d_in[3];
  const float* dt_bias = (const float*)d_in[4];
  const float* A_log   = (const float*)d_in[5];
  const float* Dp      = (const float*)d_in[6];
  const float* norm_w  = (const float*)d_in[7];
  const float* W_out   = (const float*)d_in[8];
  float* out = (float*)d_out;

  // ---- batches per pass: footprint(nb) = nb*L_*16320 + 7,385,088 ----
  const int nb = ((size_t)2 * L_ * 16320 + 7385088 <= ws_size) ? 2 : 1;
  const int rows = nb * L_;

  // ---- workspace layout (per-pass buffers) ----
  char* ws = (char*)d_ws;
  unsigned short* zseg = (unsigned short*)ws;  ws += (size_t)rows * DI * 2;   // bf16 z
  unsigned short* xbc  = (unsigned short*)ws;  ws += (size_t)rows * CD * 2;   // bf16 xBC
  _Float16* xs   = (_Float16*)ws;  ws += (size_t)rows * DI * 2;               // (ynorm home)
  _Float16* ytot = (_Float16*)ws;  ws += (size_t)rows * DI * 2;               // fp16 y
  float* Bm   = (float*)ws;  ws += (size_t)rows * DS * 4;
  float* Cm   = (float*)ws;  ws += (size_t)rows * DS * 4;
  float* dtv  = (float*)ws;  ws += (size_t)rows * H_ * 4;
  float* cumA = (float*)ws;  ws += (size_t)rows * H_ * 4;
  _Float16* Sbuf = (_Float16*)ws;  ws += (size_t)rows * 3072;  // nb*H_*NC*DS*P_*2
  unsigned short* WinT  = (unsigned short*)ws; ws += (size_t)NPJ * DM * 2;
  unsigned short* WoutT = (unsigned short*)ws; ws += (size_t)DM * DI * 2;
  float* WdtT   = (float*)ws;  ws += (size_t)H_ * DM * 4;
  unsigned short* xb    = (unsigned short*)Sbuf;     // overlay: Sbuf dead until k_intra
  unsigned short* ynorm = (unsigned short*)xs;       // overlay: xs slot free (conv fused)

  k_transpose_cast<<<dim3(24, (NPJ + 31) / 32), 256, 0, stream>>>(W_in, WinT, DM, NPJ);
  k_transpose_cast<<<dim3(48, 24), 256, 0, stream>>>(W_out, WoutT, DI, DM);
  k_wdtT<<<(H_ * DM + 255) / 256, 256, 0, stream>>>(W_in, WdtT);

  for (int b0 = 0; b0 < B_; b0 += nb) {
    const float* xp = x + (size_t)b0 * L_ * DM;

    k_dt2<<<rows / 16, 768, 0, stream>>>(xp, WdtT, dt_bias, dtv, xb);
    // in-proj: 256x128 block (512 thr), wave tile 64x64 (r6 win: 50.9us)
    k_gemm_t<256, 128, 64, 64, true><<<dim3(rows / 256, N1 / 128), 512, 0, stream>>>(
        xb, WinT, zseg, DI, DI, xbc, CD, DM);
    // slim conv: only B/C channels (DI part fused into k_intra)
    k_conv2<<<rows / CROWS, 128, 0, stream>>>(xbc, conv_w, conv_b, Bm, Cm);
    k_intra<<<dim3(NC, H_, nb), 256, 0, stream>>>(xbc, conv_w, conv_b, Bm, Cm, dtv,
                                                  A_log, Dp, cumA, ytot, Sbuf);
    k_chunkscan<<<dim3(16, H_, nb), 64, 0, stream>>>(Sbuf, cumA);
    k_inter<<<dim3(NC, H_, nb), 256, 0, stream>>>(Cm, cumA, Sbuf, ytot);
    k_rms<<<rows, 192, 0, stream>>>(zseg, ytot, norm_w, ynorm);
    // out-proj: r0-proven <128,64,64,32> -> 768 blocks = 3 even rounds on 256 CUs
    k_gemm_t<128, 64, 64, 32, false><<<dim3(rows / 128, DM / 64), 256, 0, stream>>>(
        ynorm, WoutT, out + (size_t)b0 * L_ * DM, DM, DM, out + (size_t)b0 * L_ * DM, DM, DI);
  }
}

// Round 12
// 297.716 us; speedup vs baseline: 1.0457x; 1.0116x over previous
//
#include <hip/hip_runtime.h>

// ---- problem constants ----
#define B_   2
#define L_   4096
#define DM   768
#define DI   1536     // D_INNER
#define DS   64       // D_STATE
#define H_   24       // NHEADS
#define P_   64       // HEADDIM
#define CD   1664     // CONV_DIM
#define NPJ  3224     // D_IN_PROJ
#define N1   3200     // GEMM1 useful cols (z + xBC; dt cols done exactly in k_dt2)
#define Q_   64       // chunk length
#define NC   64       // chunks per batch
#define SP   76       // LDS row stride (floats) for k_inter tiles
#define HS   72       // fp16 LDS row stride (halves): <=2-way conflicts
#define WDS  772      // k_dt2 LDS W stride (772%32=4 -> 3-way max bank aliasing)
#define CROWS 16      // conv rows per thread

typedef short          bf16x8 __attribute__((ext_vector_type(8)));
typedef _Float16       f16x8  __attribute__((ext_vector_type(8)));
typedef _Float16       f16x4  __attribute__((ext_vector_type(4)));
typedef unsigned short us8    __attribute__((ext_vector_type(8)));
typedef unsigned short us4    __attribute__((ext_vector_type(4)));
typedef float          f32x4  __attribute__((ext_vector_type(4)));

__device__ __forceinline__ unsigned short f2bf(float f) {
  unsigned u = __float_as_uint(f);
  u += 0x7fffu + ((u >> 16) & 1u);   // RNE
  return (unsigned short)(u >> 16);
}
__device__ __forceinline__ float bf2f(unsigned short u) {
  return __uint_as_float(((unsigned)u) << 16);
}
__device__ __forceinline__ float siluf(float x) { return x / (1.f + expf(-x)); }
__device__ __forceinline__ float softplusf(float x) { return (x > 20.f) ? x : log1pf(expf(x)); }

// async global->LDS, 16B per lane; LDS dest = uniform base + lane*16
__device__ __forceinline__ void gload16(const unsigned short* g, unsigned short* l) {
  __builtin_amdgcn_global_load_lds(
      (const __attribute__((address_space(1))) void*)g,
      (__attribute__((address_space(3))) void*)l, 16, 0, 0);
}

// ---------------- transpose + cast (R x C fp32) -> (C x R bf16) ----------------
__global__ __launch_bounds__(256)
void k_transpose_cast(const float* __restrict__ src, unsigned short* __restrict__ dst,
                      int R, int C)
{
  __shared__ float tile[32][33];
  const int tx = threadIdx.x & 31, ty = threadIdx.x >> 5;
  const int r0 = blockIdx.x * 32, c0 = blockIdx.y * 32;
#pragma unroll
  for (int r = 0; r < 4; ++r) {
    int rr = r0 + ty + r * 8, cc = c0 + tx;
    if (rr < R && cc < C) tile[ty + r * 8][tx] = src[(size_t)rr * C + cc];
  }
  __syncthreads();
#pragma unroll
  for (int r = 0; r < 4; ++r) {
    int orow = c0 + ty + r * 8, ocol = r0 + tx;
    if (orow < C && ocol < R) dst[(size_t)orow * R + ocol] = f2bf(tile[tx][ty + r * 8]);
  }
}

// ---------------- gather dt columns of W_in -> contiguous fp32 WdtT[24][768] ----------------
__global__ void k_wdtT(const float* __restrict__ W_in, float* __restrict__ WdtT)
{
  const int idx = blockIdx.x * 256 + threadIdx.x;
  if (idx >= H_ * DM) return;
  const int k = idx / H_, h = idx % H_;
  WdtT[(size_t)h * DM + k] = W_in[(size_t)k * NPJ + N1 + h];
}

// ---------------- bf16 MFMA GEMM, BK=64, XOR-swizzled LDS (conflict-free) ----------------
// in-proj <256,128,64,64>@512thr (r6: 50.9us); out-proj <128,64,64,32>@256thr
// (768 blocks = 3 even rounds). r6 lesson: tiles must divide the grid evenly.
template<int BM, int BN, int WM, int WN, bool OUT_BF16>
__global__ __launch_bounds__((BM / WM) * (BN / WN) * 64)
void k_gemm_t(const unsigned short* __restrict__ A, const unsigned short* __restrict__ Bt,
              void* __restrict__ C0v, int ld0, int ncol0,
              void* __restrict__ C1v, int ld1, int K)
{
  constexpr int MI = WM / 16, NI = WN / 16;
  constexpr int WAVES_N = BN / WN;
  constexpr int T  = (BM / WM) * (BN / WN) * 64;  // threads
  constexpr int RG = T / 8;                       // rows per gload band (T*16B / 128B row)
  constexpr int RA = BM / RG, RB = BN / RG;
  const int m0 = blockIdx.x * BM, n0 = blockIdx.y * BN;
  __shared__ unsigned short As[BM][64];
  __shared__ unsigned short Bs[BN][64];
  const int tid  = threadIdx.x;
  const int wave = tid >> 6, lane = tid & 63;
  const int quad = lane >> 4, r16 = lane & 15;
  const int wm = (wave / WAVES_N) * WM, wn = (wave % WAVES_N) * WN;

  const int lr8 = lane >> 3;                                // 0..7 row-in-band
  const int csw = ((lane & 7) ^ lr8) * 8;                   // swizzled source col (shorts)
  const unsigned short* gA = A  + (size_t)(m0 + wave * 8 + lr8) * K + csw;
  const unsigned short* gB = Bt + (size_t)(n0 + wave * 8 + lr8) * K + csw;
  unsigned short* lA = &As[wave * 8][0] + (size_t)lane * 8; // +lane*16B
  unsigned short* lB = &Bs[wave * 8][0] + (size_t)lane * 8;

  f32x4 acc[MI][NI];
#pragma unroll
  for (int mi = 0; mi < MI; ++mi)
#pragma unroll
    for (int ni = 0; ni < NI; ++ni) acc[mi][ni] = (f32x4){0.f, 0.f, 0.f, 0.f};

  for (int k0 = 0; k0 < K; k0 += 64) {
#pragma unroll
    for (int r = 0; r < RA; ++r)
      gload16(gA + (size_t)(r * RG) * K + k0, lA + (size_t)r * RG * 64);
#pragma unroll
    for (int r = 0; r < RB; ++r)
      gload16(gB + (size_t)(r * RG) * K + k0, lB + (size_t)r * RG * 64);
    __syncthreads();
    bf16x8 af[MI][2], bfr[NI][2];
#pragma unroll
    for (int mi = 0; mi < MI; ++mi)
#pragma unroll
      for (int ks = 0; ks < 2; ++ks)
        af[mi][ks] = *(const bf16x8*)&As[wm + mi * 16 + r16][((quad + ks * 4) ^ (r16 & 7)) * 8];
#pragma unroll
    for (int ni = 0; ni < NI; ++ni)
#pragma unroll
      for (int ks = 0; ks < 2; ++ks)
        bfr[ni][ks] = *(const bf16x8*)&Bs[wn + ni * 16 + r16][((quad + ks * 4) ^ (r16 & 7)) * 8];
#pragma unroll
    for (int mi = 0; mi < MI; ++mi)
#pragma unroll
      for (int ni = 0; ni < NI; ++ni)
#pragma unroll
        for (int ks = 0; ks < 2; ++ks)
          acc[mi][ni] = __builtin_amdgcn_mfma_f32_16x16x32_bf16(
              af[mi][ks], bfr[ni][ks], acc[mi][ni], 0, 0, 0);
    __syncthreads();
  }
#pragma unroll
  for (int mi = 0; mi < MI; ++mi)
#pragma unroll
    for (int ni = 0; ni < NI; ++ni) {
      int col = n0 + wn + ni * 16 + r16;
      void* dst; int ld, c;
      if (col < ncol0) { dst = C0v; ld = ld0; c = col; }
      else             { dst = C1v; ld = ld1; c = col - ncol0; }
#pragma unroll
      for (int r = 0; r < 4; ++r) {
        int row = m0 + wm + mi * 16 + quad * 4 + r;
        if (OUT_BF16) ((unsigned short*)dst)[(size_t)row * ld + c] = f2bf(acc[mi][ni][r]);
        else          ((float*)dst)[(size_t)row * ld + c] = acc[mi][ni][r];
      }
    }
}

// ---------------- slim conv: only B/C channels [DI, DI+128) ----------------
__global__ __launch_bounds__(128)
void k_conv2(const unsigned short* __restrict__ xbc, const float* __restrict__ cw,
             const float* __restrict__ cb, float* __restrict__ Bm, float* __restrict__ Cm)
{
  const int ch = DI + threadIdx.x;                // 128 threads: DI..DI+127
  const int r0 = blockIdx.x * CROWS;
  const float w0 = cw[ch * 4], w1 = cw[ch * 4 + 1], w2 = cw[ch * 4 + 2], w3 = cw[ch * 4 + 3];
  const float bias = cb[ch];
  float a, b, c;
  if ((r0 & (L_ - 1)) == 0) {                 // batch start: zero history
    a = 0.f; b = 0.f; c = 0.f;
  } else {
    a = bf2f(xbc[(size_t)(r0 - 3) * CD + ch]);
    b = bf2f(xbc[(size_t)(r0 - 2) * CD + ch]);
    c = bf2f(xbc[(size_t)(r0 - 1) * CD + ch]);
  }
#pragma unroll
  for (int i = 0; i < CROWS; ++i) {
    const int lr = r0 + i;
    float d = bf2f(xbc[(size_t)lr * CD + ch]);
    float v = siluf(bias + a * w0 + b * w1 + c * w2 + d * w3);
    a = b; b = c; c = d;
    if (threadIdx.x < DS) Bm[(size_t)lr * DS + threadIdx.x] = v;
    else                  Cm[(size_t)lr * DS + (threadIdx.x - DS)] = v;
  }
}

// ---------------- exact fp32 dt, v6: wave-uniform K-split x2 (r11: ~30us) ----------------
__global__ __launch_bounds__(768)
void k_dt2(const float* __restrict__ x, const float* __restrict__ WdtT,
           const float* __restrict__ dt_bias, float* __restrict__ dtv,
           unsigned short* __restrict__ xb)
{
  __shared__ float sW[H_][WDS];
  __shared__ float part[16][25];
  const int tid = threadIdx.x;
  for (int i = tid; i < H_ * DM; i += 768)
    sW[i / DM][i % DM] = WdtT[i];
  const int half = tid >> 9 | ((tid >> 8) & (tid >> 7) & 1);   // tid >= 384
  const int t2 = tid - half * 384;
  const int h = t2 % H_, rloc = t2 / H_;       // rloc 0..15
  const int row0 = blockIdx.x * 16;
  const int lrow = row0 + rloc;
  const float* xr = x + (size_t)lrow * DM + half * 384;
  const float* wr = &sW[h][half * 384];
  __syncthreads();
  float acc = 0.f;
#pragma unroll 8
  for (int k = 0; k < 384; k += 4) {
    f32x4 xv = *(const f32x4*)(xr + k);
    f32x4 wv = *(const f32x4*)(wr + k);
    acc += xv[0] * wv[0] + xv[1] * wv[1] + xv[2] * wv[2] + xv[3] * wv[3];
  }
  if (half) part[rloc][h] = acc;
  __syncthreads();
  if (!half) {
    acc += part[rloc][h];
    dtv[(size_t)lrow * H_ + h] = softplusf(acc + dt_bias[h]);
  }
  // fused x->bf16 cast: 16 rows x 768 cols / 768 thr = 16 floats each (L1-hot)
  const int crow = tid / 48, ccol = (tid % 48) * 16;
  const float* xi = x + (size_t)(row0 + crow) * DM + ccol;
  unsigned short* xo = xb + (size_t)(row0 + crow) * DM + ccol;
#pragma unroll
  for (int j = 0; j < 16; j += 8) {
    f32x4 a = *(const f32x4*)(xi + j);
    f32x4 b = *(const f32x4*)(xi + j + 4);
    us8 o;
#pragma unroll
    for (int e = 0; e < 4; ++e) { o[e] = f2bf(a[e]); o[e + 4] = f2bf(b[e]); }
    *(us8*)(xo + j) = o;
  }
}

// ---------------- intra-chunk via fp16 MFMA; ytot/Sbuf stored fp16 ----------------
// Depthwise conv for the DI channels FUSED into the x-stage (reads xbc directly).
// k_cum fused (wave-0 scan); D*x fused into the y-store.
__global__ __launch_bounds__(256)
void k_intra(const unsigned short* __restrict__ xbc, const float* __restrict__ cw,
             const float* __restrict__ cb, const float* __restrict__ Bm,
             const float* __restrict__ Cm, const float* __restrict__ dtv,
             const float* __restrict__ A_log, const float* __restrict__ Dp,
             float* __restrict__ cumA, _Float16* __restrict__ ytot,
             _Float16* __restrict__ Sbuf)
{
  const int c = blockIdx.x, h = blockIdx.y, bz = blockIdx.z;
  const int gidx = (bz * H_ + h) * NC + c;
  __shared__ _Float16 sCW[Q_][HS];   // C, then W
  __shared__ _Float16 sB [Q_][HS];
  __shared__ _Float16 sBT[Q_][HS];   // (coef_j * B[j][n]) transposed -> [n][j]
  __shared__ _Float16 sXT[Q_][HS];   // X transposed -> [p][j]
  __shared__ float scum[Q_], sdt[Q_];
  __shared__ float scw[4][Q_];       // conv weights for this head's 64 channels
  __shared__ float scb[Q_];          // conv bias
  const int tid = threadIdx.x;
  const int rowbase = bz * L_ + c * Q_;
  const int ch0 = h * P_;            // head's channel base within xbc

  {
    const int j = tid >> 2, s16 = (tid & 3) * 16;
    if (tid < Q_) {                       // wave 0 only: scan dt -> scum, emit cumA
      const float dtval = dtv[(size_t)(rowbase + tid) * H_ + h];
      sdt[tid] = dtval;
      const float A = -expf(A_log[h]);
      float v = dtval;
#pragma unroll
      for (int off = 1; off < 64; off <<= 1) {
        float o = __shfl_up(v, off, 64);
        if (tid >= off) v += o;
      }
      v *= A;
      scum[tid] = v;
      cumA[(size_t)gidx * Q_ + tid] = v;
    }
    // stage conv weights/bias for channels ch0..ch0+63 (coalesced: cw[ch0*4+tid])
    scw[tid & 3][tid >> 2] = cw[(size_t)ch0 * 4 + tid];
    if (tid < Q_) scb[tid] = cb[ch0 + tid];
    // xbc loads for conv: rows rowbase+j-3..rowbase+j, channels ch0+s16..+16
    us8 xr[4][2];
    const int rbz = bz * L_;
#pragma unroll
    for (int d = 0; d < 4; ++d) {
      const int rr = rowbase + j - 3 + d;
      const int rc = (rr < rbz) ? rbz : rr;        // clamp (loads valid ws memory)
      const unsigned short* src = xbc + (size_t)rc * CD + ch0 + s16;
      xr[d][0] = *(const us8*)src;
      xr[d][1] = *(const us8*)(src + 8);
      if (rr < rbz) {                               // zero history at batch start
        us8 z8 = {0, 0, 0, 0, 0, 0, 0, 0};
        xr[d][0] = z8; xr[d][1] = z8;
      }
    }
    f32x4 bv[4], cv[4];
    const float* bsrc = Bm + (size_t)(rowbase + j) * DS + s16;
    const float* csrc = Cm + (size_t)(rowbase + j) * DS + s16;
#pragma unroll
    for (int q = 0; q < 4; ++q) {
      bv[q] = *(const f32x4*)(bsrc + q * 4);
      cv[q] = *(const f32x4*)(csrc + q * 4);
    }
    __syncthreads();                                // covers scum, scw, scb
    const float coef = expf(scum[Q_ - 1] - scum[j]) * sdt[j];
    union { f16x8 v; _Float16 e[8]; } pc[2], pb[2];
#pragma unroll
    for (int q = 0; q < 4; ++q)
#pragma unroll
      for (int e = 0; e < 4; ++e) {
        int o = q * 4 + e;
        const int cc = s16 + o;
        pc[o >> 3].e[o & 7] = (_Float16)cv[q][e];
        pb[o >> 3].e[o & 7] = (_Float16)bv[q][e];
        sBT[cc][j] = (_Float16)(bv[q][e] * coef);
        // fused depthwise conv(4) + silu for channel ch0+cc, row rowbase+j
        float a0 = bf2f(xr[0][o >> 3][o & 7]);
        float a1 = bf2f(xr[1][o >> 3][o & 7]);
        float a2 = bf2f(xr[2][o >> 3][o & 7]);
        float a3 = bf2f(xr[3][o >> 3][o & 7]);
        float v = scb[cc] + a0 * scw[0][cc] + a1 * scw[1][cc]
                          + a2 * scw[2][cc] + a3 * scw[3][cc];
        sXT[cc][j] = (_Float16)siluf(v);
      }
    *(f16x8*)&sCW[j][s16]     = pc[0].v;
    *(f16x8*)&sCW[j][s16 + 8] = pc[1].v;
    *(f16x8*)&sB [j][s16]     = pb[0].v;
    *(f16x8*)&sB [j][s16 + 8] = pb[1].v;
  }
  __syncthreads();

  const int wave = tid >> 6, lane = tid & 63;
  const int quad = lane >> 4, r16 = lane & 15;
  const int i0 = wave * 16;
  const int irow = i0 + quad * 4;

  f32x4 g[4];
#pragma unroll
  for (int q = 0; q < 4; ++q) g[q] = (f32x4){0.f, 0.f, 0.f, 0.f};
#pragma unroll
  for (int ni = 0; ni < 4; ++ni) {
    if (ni <= wave) {
#pragma unroll
      for (int ks = 0; ks < 2; ++ks)
        g[ni] = __builtin_amdgcn_mfma_f32_16x16x32_f16(
            *(const f16x8*)&sCW[i0 + r16][ks * 32 + quad * 8],
            *(const f16x8*)&sB [ni * 16 + r16][ks * 32 + quad * 8], g[ni], 0, 0, 0);
    }
  }
  float wv[4][4];
#pragma unroll
  for (int ni = 0; ni < 4; ++ni)
#pragma unroll
    for (int r = 0; r < 4; ++r) {
      int i = irow + r, jcol = ni * 16 + r16;
      float v = 0.f;
      if (ni <= wave && jcol <= i)
        v = g[ni][r] * expf(scum[i] - scum[jcol]) * sdt[jcol];
      wv[ni][r] = v;
    }
  __syncthreads();
#pragma unroll
  for (int ni = 0; ni < 4; ++ni)
#pragma unroll
    for (int r = 0; r < 4; ++r)
      sCW[irow + r][ni * 16 + r16] = (_Float16)wv[ni][r];
  __syncthreads();

  const float Dh = Dp[h];
  f32x4 y[4];
#pragma unroll
  for (int q = 0; q < 4; ++q) y[q] = (f32x4){0.f, 0.f, 0.f, 0.f};
#pragma unroll
  for (int ni = 0; ni < 4; ++ni)
#pragma unroll
    for (int ks = 0; ks < 2; ++ks) {
      if (ks == 0 || wave >= 2)
        y[ni] = __builtin_amdgcn_mfma_f32_16x16x32_f16(
            *(const f16x8*)&sCW[i0 + r16][ks * 32 + quad * 8],
            *(const f16x8*)&sXT[ni * 16 + r16][ks * 32 + quad * 8], y[ni], 0, 0, 0);
    }
#pragma unroll
  for (int ni = 0; ni < 4; ++ni)
#pragma unroll
    for (int r = 0; r < 4; ++r) {
      const float xval = (float)sXT[ni * 16 + r16][irow + r];   // X[irow+r][ni*16+r16]
      ytot[(size_t)(rowbase + irow + r) * DI + h * P_ + ni * 16 + r16] =
          (_Float16)(y[ni][r] + Dh * xval);
    }

  f32x4 t4[4];
#pragma unroll
  for (int q = 0; q < 4; ++q) t4[q] = (f32x4){0.f, 0.f, 0.f, 0.f};
#pragma unroll
  for (int ni = 0; ni < 4; ++ni)
#pragma unroll
    for (int ks = 0; ks < 2; ++ks)
      t4[ni] = __builtin_amdgcn_mfma_f32_16x16x32_f16(
          *(const f16x8*)&sBT[i0 + r16][ks * 32 + quad * 8],
          *(const f16x8*)&sXT[ni * 16 + r16][ks * 32 + quad * 8], t4[ni], 0, 0, 0);
  _Float16* sp = Sbuf + (size_t)gidx * (DS * P_);
#pragma unroll
  for (int ni = 0; ni < 4; ++ni)
#pragma unroll
    for (int r = 0; r < 4; ++r)
      sp[(irow + r) * P_ + ni * 16 + r16] = (_Float16)t4[ni][r];
}

// ---------------- sequential inter-chunk recurrence (in-place, fp16 storage) ----------------
// 16 segments (768 waves) + group-of-8 double-buffered prefetch (proven r5).
__global__ __launch_bounds__(64)
void k_chunkscan(_Float16* __restrict__ Sbuf, const float* __restrict__ cumA)
{
  const int seg = blockIdx.x, h = blockIdx.y, bz = blockIdx.z;
  const int bh = bz * H_ + h;
  __shared__ float dec[NC];
  const int tid = threadIdx.x;
  dec[tid] = expf(cumA[((size_t)(bh * NC + tid)) * Q_ + (Q_ - 1)]);
  __syncthreads();
  _Float16* base = Sbuf + (size_t)bh * NC * (DS * P_) + (size_t)seg * 256 + (size_t)tid * 4;
  float s[4] = {0.f, 0.f, 0.f, 0.f};
  f16x4 bA[8], bB[8];
#pragma unroll
  for (int j = 0; j < 8; ++j) bA[j] = *(const f16x4*)(base + (size_t)j * (DS * P_));
#pragma unroll
  for (int g = 0; g < 8; ++g) {
    if (g + 1 < 8) {                       // prefetch next group into the other buffer
#pragma unroll
      for (int j = 0; j < 8; ++j) {
        f16x4 v = *(const f16x4*)(base + (size_t)((g + 1) * 8 + j) * (DS * P_));
        if (g & 1) bA[j] = v; else bB[j] = v;   // compile-time after full unroll
      }
    }
#pragma unroll
    for (int j = 0; j < 8; ++j) {
      const int c = g * 8 + j;
      f16x4 cur = (g & 1) ? bB[j] : bA[j];
      f16x4 sto;
#pragma unroll
      for (int e = 0; e < 4; ++e) sto[e] = (_Float16)s[e];
      *(f16x4*)(base + (size_t)c * (DS * P_)) = sto;       // state BEFORE chunk c
      const float d = dec[c];
#pragma unroll
      for (int e = 0; e < 4; ++e) s[e] = s[e] * d + (float)cur[e];
    }
  }
}

// ---------------- inter-chunk correction via fp16 MFMA (r12) ----------------
// Old k_inter was LDS-BW bound: per block 256thr x 4KB LDS reads = 1MB -> ~3GB
// total ~45us at 69TB/s. Now Ycorr = C(64x64) @ S(64x64) on the matrix pipe:
// stage C as fp16 (same treatment as k_intra's sCW) and S transposed; 8 MFMA
// per wave; epilogue ytot += exp(scum[i]) * acc (same RMW pattern as k_intra).
__global__ __launch_bounds__(256)
void k_inter(const float* __restrict__ Cm, const float* __restrict__ cumA,
             const _Float16* __restrict__ Sbuf, _Float16* __restrict__ ytot)
{
  const int c = blockIdx.x, h = blockIdx.y, bz = blockIdx.z;
  const int gidx = (bz * H_ + h) * NC + c;
  __shared__ _Float16 sCf[Q_][HS];   // C rows (fp16), [i][n]
  __shared__ _Float16 sST[P_][HS];   // S transposed, [p][n]
  __shared__ float scum[Q_];
  const int tid = threadIdx.x;
  const int jr = tid >> 2, blk = (tid & 3) * 16;
  const int rowbase = bz * L_ + c * Q_;
  {
    // S[jr][blk..blk+16] -> sST[blk+o][jr]  (same scatter pattern as k_intra sBT)
    const _Float16* ssrc = Sbuf + (size_t)gidx * (DS * P_) + jr * P_ + blk;
    f16x8 sv0 = *(const f16x8*)ssrc;
    f16x8 sv1 = *(const f16x8*)(ssrc + 8);
#pragma unroll
    for (int o = 0; o < 8; ++o) {
      sST[blk + o][jr]     = sv0[o];
      sST[blk + 8 + o][jr] = sv1[o];
    }
    // C[jr][blk..blk+16] -> fp16 row-major
    const float* csrc = Cm + (size_t)(rowbase + jr) * DS + blk;
    union { f16x8 v; _Float16 e[8]; } pc[2];
#pragma unroll
    for (int q = 0; q < 4; ++q) {
      f32x4 cv = *(const f32x4*)(csrc + q * 4);
#pragma unroll
      for (int e = 0; e < 4; ++e) pc[q >> 1].e[(q & 1) * 4 + e] = (_Float16)cv[e];
    }
    *(f16x8*)&sCf[jr][blk]     = pc[0].v;
    *(f16x8*)&sCf[jr][blk + 8] = pc[1].v;
    if (tid < Q_) scum[tid] = cumA[(size_t)gidx * Q_ + tid];
  }
  __syncthreads();

  const int wave = tid >> 6, lane = tid & 63;
  const int quad = lane >> 4, r16 = lane & 15;
  const int i0 = wave * 16;
  const int irow = i0 + quad * 4;

  f32x4 acc[4];
#pragma unroll
  for (int q = 0; q < 4; ++q) acc[q] = (f32x4){0.f, 0.f, 0.f, 0.f};
#pragma unroll
  for (int ni = 0; ni < 4; ++ni)
#pragma unroll
    for (int ks = 0; ks < 2; ++ks)
      acc[ni] = __builtin_amdgcn_mfma_f32_16x16x32_f16(
          *(const f16x8*)&sCf[i0 + r16][ks * 32 + quad * 8],
          *(const f16x8*)&sST[ni * 16 + r16][ks * 32 + quad * 8], acc[ni], 0, 0, 0);

  float e4[4];
#pragma unroll
  for (int r = 0; r < 4; ++r) e4[r] = expf(scum[irow + r]);
#pragma unroll
  for (int ni = 0; ni < 4; ++ni)
#pragma unroll
    for (int r = 0; r < 4; ++r) {
      _Float16* yt = ytot + (size_t)(rowbase + irow + r) * DI + h * P_ + ni * 16 + r16;
      *yt = (_Float16)((float)*yt + e4[r] * acc[ni][r]);
    }
}

// ---------------- gate (silu(z)) + RMSNorm + cast bf16 ----------------
__global__ __launch_bounds__(192)
void k_rms(const unsigned short* __restrict__ z, const _Float16* __restrict__ ytot,
           const float* __restrict__ norm_w, unsigned short* __restrict__ ynorm)
{
  const int row = blockIdx.x, tid = threadIdx.x;
  const int e0 = tid * 8;
  us8 zv = *(const us8*)(z + (size_t)row * DI + e0);
  f16x8 yv = *(const f16x8*)(ytot + (size_t)row * DI + e0);
  float g[8];
  float ss = 0.f;
#pragma unroll
  for (int q = 0; q < 8; ++q) {
    g[q] = (float)yv[q] * siluf(bf2f(zv[q]));
    ss += g[q] * g[q];
  }
#pragma unroll
  for (int off = 32; off > 0; off >>= 1) ss += __shfl_down(ss, off);
  __shared__ float wsum[3];
  __shared__ float sscale;
  if ((tid & 63) == 0) wsum[tid >> 6] = ss;
  __syncthreads();
  if (tid == 0) sscale = rsqrtf((wsum[0] + wsum[1] + wsum[2]) * (1.f / DI) + 1e-5f);
  __syncthreads();
  const float sc = sscale;
  us8 o;
#pragma unroll
  for (int q = 0; q < 8; ++q) o[q] = f2bf(g[q] * sc * norm_w[e0 + q]);
  *(us8*)(ynorm + (size_t)row * DI + e0) = o;
}

extern "C" void kernel_launch(void* const* d_in, const int* in_sizes, int n_in,
                              void* d_out, int out_size, void* d_ws, size_t ws_size,
                              hipStream_t stream)
{
  (void)in_sizes; (void)n_in; (void)out_size;
  const float* x       = (const float*)d_in[0];
  const float* W_in    = (const float*)d_in[1];
  const float* conv_w  = (const float*)d_in[2];
  const float* conv_b  = (const float*)d_in[3];
  const float* dt_bias = (const float*)d_in[4];
  const float* A_log   = (const float*)d_in[5];
  const float* Dp      = (const float*)d_in[6];
  const float* norm_w  = (const float*)d_in[7];
  const float* W_out   = (const float*)d_in[8];
  float* out = (float*)d_out;

  // ---- batches per pass: footprint(nb) = nb*L_*16320 + 7,385,088 ----
  const int nb = ((size_t)2 * L_ * 16320 + 7385088 <= ws_size) ? 2 : 1;
  const int rows = nb * L_;

  // ---- workspace layout (per-pass buffers) ----
  char* ws = (char*)d_ws;
  unsigned short* zseg = (unsigned short*)ws;  ws += (size_t)rows * DI * 2;   // bf16 z
  unsigned short* xbc  = (unsigned short*)ws;  ws += (size_t)rows * CD * 2;   // bf16 xBC
  _Float16* xs   = (_Float16*)ws;  ws += (size_t)rows * DI * 2;               // (ynorm home)
  _Float16* ytot = (_Float16*)ws;  ws += (size_t)rows * DI * 2;               // fp16 y
  float* Bm   = (float*)ws;  ws += (size_t)rows * DS * 4;
  float* Cm   = (float*)ws;  ws += (size_t)rows * DS * 4;
  float* dtv  = (float*)ws;  ws += (size_t)rows * H_ * 4;
  float* cumA = (float*)ws;  ws += (size_t)rows * H_ * 4;
  _Float16* Sbuf = (_Float16*)ws;  ws += (size_t)rows * 3072;  // nb*H_*NC*DS*P_*2
  unsigned short* WinT  = (unsigned short*)ws; ws += (size_t)NPJ * DM * 2;
  unsigned short* WoutT = (unsigned short*)ws; ws += (size_t)DM * DI * 2;
  float* WdtT   = (float*)ws;  ws += (size_t)H_ * DM * 4;
  unsigned short* xb    = (unsigned short*)Sbuf;     // overlay: Sbuf dead until k_intra
  unsigned short* ynorm = (unsigned short*)xs;       // overlay: xs slot free (conv fused)

  k_transpose_cast<<<dim3(24, (NPJ + 31) / 32), 256, 0, stream>>>(W_in, WinT, DM, NPJ);
  k_transpose_cast<<<dim3(48, 24), 256, 0, stream>>>(W_out, WoutT, DI, DM);
  k_wdtT<<<(H_ * DM + 255) / 256, 256, 0, stream>>>(W_in, WdtT);

  for (int b0 = 0; b0 < B_; b0 += nb) {
    const float* xp = x + (size_t)b0 * L_ * DM;

    k_dt2<<<rows / 16, 768, 0, stream>>>(xp, WdtT, dt_bias, dtv, xb);
    // in-proj: 256x128 block (512 thr), wave tile 64x64 (r6 win: 50.9us)
    k_gemm_t<256, 128, 64, 64, true><<<dim3(rows / 256, N1 / 128), 512, 0, stream>>>(
        xb, WinT, zseg, DI, DI, xbc, CD, DM);
    // slim conv: only B/C channels (DI part fused into k_intra)
    k_conv2<<<rows / CROWS, 128, 0, stream>>>(xbc, conv_w, conv_b, Bm, Cm);
    k_intra<<<dim3(NC, H_, nb), 256, 0, stream>>>(xbc, conv_w, conv_b, Bm, Cm, dtv,
                                                  A_log, Dp, cumA, ytot, Sbuf);
    k_chunkscan<<<dim3(16, H_, nb), 64, 0, stream>>>(Sbuf, cumA);
    k_inter<<<dim3(NC, H_, nb), 256, 0, stream>>>(Cm, cumA, Sbuf, ytot);
    k_rms<<<rows, 192, 0, stream>>>(zseg, ytot, norm_w, ynorm);
    // out-proj: r0-proven <128,64,64,32> -> 768 blocks = 3 even rounds on 256 CUs
    k_gemm_t<128, 64, 64, 32, false><<<dim3(rows / 128, DM / 64), 256, 0, stream>>>(
        ynorm, WoutT, out + (size_t)b0 * L_ * DM, DM, DM, out + (size_t)b0 * L_ * DM, DM, DI);
  }
}

// Round 14
// 274.529 us; speedup vs baseline: 1.1340x; 1.0845x over previous
//
#include <hip/hip_runtime.h>

// ---- problem constants ----
#define B_   2
#define L_   4096
#define DM   768
#define DI   1536     // D_INNER
#define DS   64       // D_STATE
#define H_   24       // NHEADS
#define P_   64       // HEADDIM
#define CD   1664     // CONV_DIM
#define NPJ  3224     // D_IN_PROJ
#define N1   3200     // GEMM1 useful cols (z + xBC; dt cols done exactly in k_dt2)
#define Q_   64       // chunk length
#define NC   64       // chunks per batch
#define SP   76       // LDS row stride (floats) for k_inter tiles
#define HS   72       // fp16 LDS row stride (halves): <=2-way conflicts
#define WDS  772      // k_dt2 LDS W stride (772%32=4 -> 3-way max bank aliasing)
#define CROWS 16      // conv rows per thread

typedef short          bf16x8 __attribute__((ext_vector_type(8)));
typedef _Float16       f16x8  __attribute__((ext_vector_type(8)));
typedef _Float16       f16x4  __attribute__((ext_vector_type(4)));
typedef _Float16       f16x2  __attribute__((ext_vector_type(2)));
typedef unsigned short us8    __attribute__((ext_vector_type(8)));
typedef unsigned short us4    __attribute__((ext_vector_type(4)));
typedef float          f32x4  __attribute__((ext_vector_type(4)));

__device__ __forceinline__ unsigned short f2bf(float f) {
  unsigned u = __float_as_uint(f);
  u += 0x7fffu + ((u >> 16) & 1u);   // RNE
  return (unsigned short)(u >> 16);
}
__device__ __forceinline__ float bf2f(unsigned short u) {
  return __uint_as_float(((unsigned)u) << 16);
}
__device__ __forceinline__ float siluf(float x) { return x / (1.f + expf(-x)); }
__device__ __forceinline__ float softplusf(float x) { return (x > 20.f) ? x : log1pf(expf(x)); }

// async global->LDS, 16B per lane; LDS dest = uniform base + lane*16
__device__ __forceinline__ void gload16(const unsigned short* g, unsigned short* l) {
  __builtin_amdgcn_global_load_lds(
      (const __attribute__((address_space(1))) void*)g,
      (__attribute__((address_space(3))) void*)l, 16, 0, 0);
}

// ---------------- transpose + cast (R x C fp32) -> (C x R bf16) ----------------
__global__ __launch_bounds__(256)
void k_transpose_cast(const float* __restrict__ src, unsigned short* __restrict__ dst,
                      int R, int C)
{
  __shared__ float tile[32][33];
  const int tx = threadIdx.x & 31, ty = threadIdx.x >> 5;
  const int r0 = blockIdx.x * 32, c0 = blockIdx.y * 32;
#pragma unroll
  for (int r = 0; r < 4; ++r) {
    int rr = r0 + ty + r * 8, cc = c0 + tx;
    if (rr < R && cc < C) tile[ty + r * 8][tx] = src[(size_t)rr * C + cc];
  }
  __syncthreads();
#pragma unroll
  for (int r = 0; r < 4; ++r) {
    int orow = c0 + ty + r * 8, ocol = r0 + tx;
    if (orow < C && ocol < R) dst[(size_t)orow * R + ocol] = f2bf(tile[tx][ty + r * 8]);
  }
}

// ---------------- gather dt columns of W_in -> contiguous fp32 WdtT[24][768] ----------------
__global__ void k_wdtT(const float* __restrict__ W_in, float* __restrict__ WdtT)
{
  const int idx = blockIdx.x * 256 + threadIdx.x;
  if (idx >= H_ * DM) return;
  const int k = idx / H_, h = idx % H_;
  WdtT[(size_t)h * DM + k] = W_in[(size_t)k * NPJ + N1 + h];
}

// ---------------- bf16 MFMA GEMM, BK=64, XOR-swizzled LDS (conflict-free) ----------------
// in-proj <256,128,64,64>@512thr (r6: 50.9us); out-proj <128,64,64,32>@256thr
// (768 blocks = 3 even rounds). r6 lesson: tiles must divide the grid evenly.
template<int BM, int BN, int WM, int WN, bool OUT_BF16>
__global__ __launch_bounds__((BM / WM) * (BN / WN) * 64)
void k_gemm_t(const unsigned short* __restrict__ A, const unsigned short* __restrict__ Bt,
              void* __restrict__ C0v, int ld0, int ncol0,
              void* __restrict__ C1v, int ld1, int K)
{
  constexpr int MI = WM / 16, NI = WN / 16;
  constexpr int WAVES_N = BN / WN;
  constexpr int T  = (BM / WM) * (BN / WN) * 64;  // threads
  constexpr int RG = T / 8;                       // rows per gload band (T*16B / 128B row)
  constexpr int RA = BM / RG, RB = BN / RG;
  const int m0 = blockIdx.x * BM, n0 = blockIdx.y * BN;
  __shared__ unsigned short As[BM][64];
  __shared__ unsigned short Bs[BN][64];
  const int tid  = threadIdx.x;
  const int wave = tid >> 6, lane = tid & 63;
  const int quad = lane >> 4, r16 = lane & 15;
  const int wm = (wave / WAVES_N) * WM, wn = (wave % WAVES_N) * WN;

  const int lr8 = lane >> 3;                                // 0..7 row-in-band
  const int csw = ((lane & 7) ^ lr8) * 8;                   // swizzled source col (shorts)
  const unsigned short* gA = A  + (size_t)(m0 + wave * 8 + lr8) * K + csw;
  const unsigned short* gB = Bt + (size_t)(n0 + wave * 8 + lr8) * K + csw;
  unsigned short* lA = &As[wave * 8][0] + (size_t)lane * 8; // +lane*16B
  unsigned short* lB = &Bs[wave * 8][0] + (size_t)lane * 8;

  f32x4 acc[MI][NI];
#pragma unroll
  for (int mi = 0; mi < MI; ++mi)
#pragma unroll
    for (int ni = 0; ni < NI; ++ni) acc[mi][ni] = (f32x4){0.f, 0.f, 0.f, 0.f};

  for (int k0 = 0; k0 < K; k0 += 64) {
#pragma unroll
    for (int r = 0; r < RA; ++r)
      gload16(gA + (size_t)(r * RG) * K + k0, lA + (size_t)r * RG * 64);
#pragma unroll
    for (int r = 0; r < RB; ++r)
      gload16(gB + (size_t)(r * RG) * K + k0, lB + (size_t)r * RG * 64);
    __syncthreads();
    bf16x8 af[MI][2], bfr[NI][2];
#pragma unroll
    for (int mi = 0; mi < MI; ++mi)
#pragma unroll
      for (int ks = 0; ks < 2; ++ks)
        af[mi][ks] = *(const bf16x8*)&As[wm + mi * 16 + r16][((quad + ks * 4) ^ (r16 & 7)) * 8];
#pragma unroll
    for (int ni = 0; ni < NI; ++ni)
#pragma unroll
      for (int ks = 0; ks < 2; ++ks)
        bfr[ni][ks] = *(const bf16x8*)&Bs[wn + ni * 16 + r16][((quad + ks * 4) ^ (r16 & 7)) * 8];
#pragma unroll
    for (int mi = 0; mi < MI; ++mi)
#pragma unroll
      for (int ni = 0; ni < NI; ++ni)
#pragma unroll
        for (int ks = 0; ks < 2; ++ks)
          acc[mi][ni] = __builtin_amdgcn_mfma_f32_16x16x32_bf16(
              af[mi][ks], bfr[ni][ks], acc[mi][ni], 0, 0, 0);
    __syncthreads();
  }
#pragma unroll
  for (int mi = 0; mi < MI; ++mi)
#pragma unroll
    for (int ni = 0; ni < NI; ++ni) {
      int col = n0 + wn + ni * 16 + r16;
      void* dst; int ld, c;
      if (col < ncol0) { dst = C0v; ld = ld0; c = col; }
      else             { dst = C1v; ld = ld1; c = col - ncol0; }
#pragma unroll
      for (int r = 0; r < 4; ++r) {
        int row = m0 + wm + mi * 16 + quad * 4 + r;
        if (OUT_BF16) ((unsigned short*)dst)[(size_t)row * ld + c] = f2bf(acc[mi][ni][r]);
        else          ((float*)dst)[(size_t)row * ld + c] = acc[mi][ni][r];
      }
    }
}

// ---------------- slim conv: only B/C channels [DI, DI+128) ----------------
__global__ __launch_bounds__(128)
void k_conv2(const unsigned short* __restrict__ xbc, const float* __restrict__ cw,
             const float* __restrict__ cb, float* __restrict__ Bm, float* __restrict__ Cm)
{
  const int ch = DI + threadIdx.x;                // 128 threads: DI..DI+127
  const int r0 = blockIdx.x * CROWS;
  const float w0 = cw[ch * 4], w1 = cw[ch * 4 + 1], w2 = cw[ch * 4 + 2], w3 = cw[ch * 4 + 3];
  const float bias = cb[ch];
  float a, b, c;
  if ((r0 & (L_ - 1)) == 0) {                 // batch start: zero history
    a = 0.f; b = 0.f; c = 0.f;
  } else {
    a = bf2f(xbc[(size_t)(r0 - 3) * CD + ch]);
    b = bf2f(xbc[(size_t)(r0 - 2) * CD + ch]);
    c = bf2f(xbc[(size_t)(r0 - 1) * CD + ch]);
  }
#pragma unroll
  for (int i = 0; i < CROWS; ++i) {
    const int lr = r0 + i;
    float d = bf2f(xbc[(size_t)lr * CD + ch]);
    float v = siluf(bias + a * w0 + b * w1 + c * w2 + d * w3);
    a = b; b = c; c = d;
    if (threadIdx.x < DS) Bm[(size_t)lr * DS + threadIdx.x] = v;
    else                  Cm[(size_t)lr * DS + (threadIdx.x - DS)] = v;
  }
}

// ---------------- exact fp32 dt, v6: wave-uniform K-split x2 (r11: ~30us) ----------------
__global__ __launch_bounds__(768)
void k_dt2(const float* __restrict__ x, const float* __restrict__ WdtT,
           const float* __restrict__ dt_bias, float* __restrict__ dtv,
           unsigned short* __restrict__ xb)
{
  __shared__ float sW[H_][WDS];
  __shared__ float part[16][25];
  const int tid = threadIdx.x;
  for (int i = tid; i < H_ * DM; i += 768)
    sW[i / DM][i % DM] = WdtT[i];
  const int half = tid >> 9 | ((tid >> 8) & (tid >> 7) & 1);   // tid >= 384
  const int t2 = tid - half * 384;
  const int h = t2 % H_, rloc = t2 / H_;       // rloc 0..15
  const int row0 = blockIdx.x * 16;
  const int lrow = row0 + rloc;
  const float* xr = x + (size_t)lrow * DM + half * 384;
  const float* wr = &sW[h][half * 384];
  __syncthreads();
  float acc = 0.f;
#pragma unroll 8
  for (int k = 0; k < 384; k += 4) {
    f32x4 xv = *(const f32x4*)(xr + k);
    f32x4 wv = *(const f32x4*)(wr + k);
    acc += xv[0] * wv[0] + xv[1] * wv[1] + xv[2] * wv[2] + xv[3] * wv[3];
  }
  if (half) part[rloc][h] = acc;
  __syncthreads();
  if (!half) {
    acc += part[rloc][h];
    dtv[(size_t)lrow * H_ + h] = softplusf(acc + dt_bias[h]);
  }
  // fused x->bf16 cast: 16 rows x 768 cols / 768 thr = 16 floats each (L1-hot)
  const int crow = tid / 48, ccol = (tid % 48) * 16;
  const float* xi = x + (size_t)(row0 + crow) * DM + ccol;
  unsigned short* xo = xb + (size_t)(row0 + crow) * DM + ccol;
#pragma unroll
  for (int j = 0; j < 16; j += 8) {
    f32x4 a = *(const f32x4*)(xi + j);
    f32x4 b = *(const f32x4*)(xi + j + 4);
    us8 o;
#pragma unroll
    for (int e = 0; e < 4; ++e) { o[e] = f2bf(a[e]); o[e + 4] = f2bf(b[e]); }
    *(us8*)(xo + j) = o;
  }
}

// ---------------- intra-chunk via fp16 MFMA; ytot/Sbuf stored fp16 ----------------
// Depthwise conv for the DI channels FUSED into the x-stage (reads xbc directly).
// k_cum fused (wave-0 scan); D*x fused into the y-store.
__global__ __launch_bounds__(256)
void k_intra(const unsigned short* __restrict__ xbc, const float* __restrict__ cw,
             const float* __restrict__ cb, const float* __restrict__ Bm,
             const float* __restrict__ Cm, const float* __restrict__ dtv,
             const float* __restrict__ A_log, const float* __restrict__ Dp,
             float* __restrict__ cumA, _Float16* __restrict__ ytot,
             _Float16* __restrict__ Sbuf)
{
  const int c = blockIdx.x, h = blockIdx.y, bz = blockIdx.z;
  const int gidx = (bz * H_ + h) * NC + c;
  __shared__ _Float16 sCW[Q_][HS];   // C, then W
  __shared__ _Float16 sB [Q_][HS];
  __shared__ _Float16 sBT[Q_][HS];   // (coef_j * B[j][n]) transposed -> [n][j]
  __shared__ _Float16 sXT[Q_][HS];   // X transposed -> [p][j]
  __shared__ float scum[Q_], sdt[Q_];
  __shared__ float scw[4][Q_];       // conv weights for this head's 64 channels
  __shared__ float scb[Q_];          // conv bias
  const int tid = threadIdx.x;
  const int rowbase = bz * L_ + c * Q_;
  const int ch0 = h * P_;            // head's channel base within xbc

  {
    const int j = tid >> 2, s16 = (tid & 3) * 16;
    if (tid < Q_) {                       // wave 0 only: scan dt -> scum, emit cumA
      const float dtval = dtv[(size_t)(rowbase + tid) * H_ + h];
      sdt[tid] = dtval;
      const float A = -expf(A_log[h]);
      float v = dtval;
#pragma unroll
      for (int off = 1; off < 64; off <<= 1) {
        float o = __shfl_up(v, off, 64);
        if (tid >= off) v += o;
      }
      v *= A;
      scum[tid] = v;
      cumA[(size_t)gidx * Q_ + tid] = v;
    }
    // stage conv weights/bias for channels ch0..ch0+63 (coalesced: cw[ch0*4+tid])
    scw[tid & 3][tid >> 2] = cw[(size_t)ch0 * 4 + tid];
    if (tid < Q_) scb[tid] = cb[ch0 + tid];
    // xbc loads for conv: rows rowbase+j-3..rowbase+j, channels ch0+s16..+16
    us8 xr[4][2];
    const int rbz = bz * L_;
#pragma unroll
    for (int d = 0; d < 4; ++d) {
      const int rr = rowbase + j - 3 + d;
      const int rc = (rr < rbz) ? rbz : rr;        // clamp (loads valid ws memory)
      const unsigned short* src = xbc + (size_t)rc * CD + ch0 + s16;
      xr[d][0] = *(const us8*)src;
      xr[d][1] = *(const us8*)(src + 8);
      if (rr < rbz) {                               // zero history at batch start
        us8 z8 = {0, 0, 0, 0, 0, 0, 0, 0};
        xr[d][0] = z8; xr[d][1] = z8;
      }
    }
    f32x4 bv[4], cv[4];
    const float* bsrc = Bm + (size_t)(rowbase + j) * DS + s16;
    const float* csrc = Cm + (size_t)(rowbase + j) * DS + s16;
#pragma unroll
    for (int q = 0; q < 4; ++q) {
      bv[q] = *(const f32x4*)(bsrc + q * 4);
      cv[q] = *(const f32x4*)(csrc + q * 4);
    }
    __syncthreads();                                // covers scum, scw, scb
    const float coef = expf(scum[Q_ - 1] - scum[j]) * sdt[j];
    union { f16x8 v; _Float16 e[8]; } pc[2], pb[2];
#pragma unroll
    for (int q = 0; q < 4; ++q)
#pragma unroll
      for (int e = 0; e < 4; ++e) {
        int o = q * 4 + e;
        const int cc = s16 + o;
        pc[o >> 3].e[o & 7] = (_Float16)cv[q][e];
        pb[o >> 3].e[o & 7] = (_Float16)bv[q][e];
        sBT[cc][j] = (_Float16)(bv[q][e] * coef);
        // fused depthwise conv(4) + silu for channel ch0+cc, row rowbase+j
        float a0 = bf2f(xr[0][o >> 3][o & 7]);
        float a1 = bf2f(xr[1][o >> 3][o & 7]);
        float a2 = bf2f(xr[2][o >> 3][o & 7]);
        float a3 = bf2f(xr[3][o >> 3][o & 7]);
        float v = scb[cc] + a0 * scw[0][cc] + a1 * scw[1][cc]
                          + a2 * scw[2][cc] + a3 * scw[3][cc];
        sXT[cc][j] = (_Float16)siluf(v);
      }
    *(f16x8*)&sCW[j][s16]     = pc[0].v;
    *(f16x8*)&sCW[j][s16 + 8] = pc[1].v;
    *(f16x8*)&sB [j][s16]     = pb[0].v;
    *(f16x8*)&sB [j][s16 + 8] = pb[1].v;
  }
  __syncthreads();

  const int wave = tid >> 6, lane = tid & 63;
  const int quad = lane >> 4, r16 = lane & 15;
  const int i0 = wave * 16;
  const int irow = i0 + quad * 4;

  f32x4 g[4];
#pragma unroll
  for (int q = 0; q < 4; ++q) g[q] = (f32x4){0.f, 0.f, 0.f, 0.f};
#pragma unroll
  for (int ni = 0; ni < 4; ++ni) {
    if (ni <= wave) {
#pragma unroll
      for (int ks = 0; ks < 2; ++ks)
        g[ni] = __builtin_amdgcn_mfma_f32_16x16x32_f16(
            *(const f16x8*)&sCW[i0 + r16][ks * 32 + quad * 8],
            *(const f16x8*)&sB [ni * 16 + r16][ks * 32 + quad * 8], g[ni], 0, 0, 0);
    }
  }
  float wv[4][4];
#pragma unroll
  for (int ni = 0; ni < 4; ++ni)
#pragma unroll
    for (int r = 0; r < 4; ++r) {
      int i = irow + r, jcol = ni * 16 + r16;
      float v = 0.f;
      if (ni <= wave && jcol <= i)
        v = g[ni][r] * expf(scum[i] - scum[jcol]) * sdt[jcol];
      wv[ni][r] = v;
    }
  __syncthreads();
#pragma unroll
  for (int ni = 0; ni < 4; ++ni)
#pragma unroll
    for (int r = 0; r < 4; ++r)
      sCW[irow + r][ni * 16 + r16] = (_Float16)wv[ni][r];
  __syncthreads();

  const float Dh = Dp[h];
  f32x4 y[4];
#pragma unroll
  for (int q = 0; q < 4; ++q) y[q] = (f32x4){0.f, 0.f, 0.f, 0.f};
#pragma unroll
  for (int ni = 0; ni < 4; ++ni)
#pragma unroll
    for (int ks = 0; ks < 2; ++ks) {
      if (ks == 0 || wave >= 2)
        y[ni] = __builtin_amdgcn_mfma_f32_16x16x32_f16(
            *(const f16x8*)&sCW[i0 + r16][ks * 32 + quad * 8],
            *(const f16x8*)&sXT[ni * 16 + r16][ks * 32 + quad * 8], y[ni], 0, 0, 0);
    }
#pragma unroll
  for (int ni = 0; ni < 4; ++ni)
#pragma unroll
    for (int r = 0; r < 4; ++r) {
      const float xval = (float)sXT[ni * 16 + r16][irow + r];   // X[irow+r][ni*16+r16]
      ytot[(size_t)(rowbase + irow + r) * DI + h * P_ + ni * 16 + r16] =
          (_Float16)(y[ni][r] + Dh * xval);
    }

  f32x4 t4[4];
#pragma unroll
  for (int q = 0; q < 4; ++q) t4[q] = (f32x4){0.f, 0.f, 0.f, 0.f};
#pragma unroll
  for (int ni = 0; ni < 4; ++ni)
#pragma unroll
    for (int ks = 0; ks < 2; ++ks)
      t4[ni] = __builtin_amdgcn_mfma_f32_16x16x32_f16(
          *(const f16x8*)&sBT[i0 + r16][ks * 32 + quad * 8],
          *(const f16x8*)&sXT[ni * 16 + r16][ks * 32 + quad * 8], t4[ni], 0, 0, 0);
  _Float16* sp = Sbuf + (size_t)gidx * (DS * P_);
#pragma unroll
  for (int ni = 0; ni < 4; ++ni)
#pragma unroll
    for (int r = 0; r < 4; ++r)
      sp[(irow + r) * P_ + ni * 16 + r16] = (_Float16)t4[ni][r];
}

// ---------------- sequential inter-chunk recurrence (in-place, fp16 storage) ----------------
// r13: 32 segments (1536 waves = 1.5/SIMD, was 0.75) x f16x2; same group-of-8
// double-buffered prefetch. Loads stay fully coalesced (64 lanes x 4B = 256B).
__global__ __launch_bounds__(64)
void k_chunkscan(_Float16* __restrict__ Sbuf, const float* __restrict__ cumA)
{
  const int seg = blockIdx.x, h = blockIdx.y, bz = blockIdx.z;
  const int bh = bz * H_ + h;
  __shared__ float dec[NC];
  const int tid = threadIdx.x;
  dec[tid] = expf(cumA[((size_t)(bh * NC + tid)) * Q_ + (Q_ - 1)]);
  __syncthreads();
  _Float16* base = Sbuf + (size_t)bh * NC * (DS * P_) + (size_t)seg * 128 + (size_t)tid * 2;
  float s0 = 0.f, s1 = 0.f;
  f16x2 bA[8], bB[8];
#pragma unroll
  for (int j = 0; j < 8; ++j) bA[j] = *(const f16x2*)(base + (size_t)j * (DS * P_));
#pragma unroll
  for (int g = 0; g < 8; ++g) {
    if (g + 1 < 8) {                       // prefetch next group into the other buffer
#pragma unroll
      for (int j = 0; j < 8; ++j) {
        f16x2 v = *(const f16x2*)(base + (size_t)((g + 1) * 8 + j) * (DS * P_));
        if (g & 1) bA[j] = v; else bB[j] = v;   // compile-time after full unroll
      }
    }
#pragma unroll
    for (int j = 0; j < 8; ++j) {
      const int c = g * 8 + j;
      f16x2 cur = (g & 1) ? bB[j] : bA[j];
      f16x2 sto;
      sto[0] = (_Float16)s0; sto[1] = (_Float16)s1;
      *(f16x2*)(base + (size_t)c * (DS * P_)) = sto;       // state BEFORE chunk c
      const float d = dec[c];
      s0 = s0 * d + (float)cur[0];
      s1 = s1 * d + (float)cur[1];
    }
  }
}

// ---------------- inter-chunk correction via fp16 MFMA (r12: ~15us) ----------------
__global__ __launch_bounds__(256)
void k_inter(const float* __restrict__ Cm, const float* __restrict__ cumA,
             const _Float16* __restrict__ Sbuf, _Float16* __restrict__ ytot)
{
  const int c = blockIdx.x, h = blockIdx.y, bz = blockIdx.z;
  const int gidx = (bz * H_ + h) * NC + c;
  __shared__ _Float16 sCf[Q_][HS];   // C rows (fp16), [i][n]
  __shared__ _Float16 sST[P_][HS];   // S transposed, [p][n]
  __shared__ float scum[Q_];
  const int tid = threadIdx.x;
  const int jr = tid >> 2, blk = (tid & 3) * 16;
  const int rowbase = bz * L_ + c * Q_;
  {
    // S[jr][blk..blk+16] -> sST[blk+o][jr]  (same scatter pattern as k_intra sBT)
    const _Float16* ssrc = Sbuf + (size_t)gidx * (DS * P_) + jr * P_ + blk;
    f16x8 sv0 = *(const f16x8*)ssrc;
    f16x8 sv1 = *(const f16x8*)(ssrc + 8);
#pragma unroll
    for (int o = 0; o < 8; ++o) {
      sST[blk + o][jr]     = sv0[o];
      sST[blk + 8 + o][jr] = sv1[o];
    }
    // C[jr][blk..blk+16] -> fp16 row-major
    const float* csrc = Cm + (size_t)(rowbase + jr) * DS + blk;
    union { f16x8 v; _Float16 e[8]; } pc[2];
#pragma unroll
    for (int q = 0; q < 4; ++q) {
      f32x4 cv = *(const f32x4*)(csrc + q * 4);
#pragma unroll
      for (int e = 0; e < 4; ++e) pc[q >> 1].e[(q & 1) * 4 + e] = (_Float16)cv[e];
    }
    *(f16x8*)&sCf[jr][blk]     = pc[0].v;
    *(f16x8*)&sCf[jr][blk + 8] = pc[1].v;
    if (tid < Q_) scum[tid] = cumA[(size_t)gidx * Q_ + tid];
  }
  __syncthreads();

  const int wave = tid >> 6, lane = tid & 63;
  const int quad = lane >> 4, r16 = lane & 15;
  const int i0 = wave * 16;
  const int irow = i0 + quad * 4;

  f32x4 acc[4];
#pragma unroll
  for (int q = 0; q < 4; ++q) acc[q] = (f32x4){0.f, 0.f, 0.f, 0.f};
#pragma unroll
  for (int ni = 0; ni < 4; ++ni)
#pragma unroll
    for (int ks = 0; ks < 2; ++ks)
      acc[ni] = __builtin_amdgcn_mfma_f32_16x16x32_f16(
          *(const f16x8*)&sCf[i0 + r16][ks * 32 + quad * 8],
          *(const f16x8*)&sST[ni * 16 + r16][ks * 32 + quad * 8], acc[ni], 0, 0, 0);

  float e4[4];
#pragma unroll
  for (int r = 0; r < 4; ++r) e4[r] = expf(scum[irow + r]);
#pragma unroll
  for (int ni = 0; ni < 4; ++ni)
#pragma unroll
    for (int r = 0; r < 4; ++r) {
      _Float16* yt = ytot + (size_t)(rowbase + irow + r) * DI + h * P_ + ni * 16 + r16;
      *yt = (_Float16)((float)*yt + e4[r] * acc[ni][r]);
    }
}

// ---------------- gate (silu(z)) + RMSNorm + cast bf16 ----------------
__global__ __launch_bounds__(192)
void k_rms(const unsigned short* __restrict__ z, const _Float16* __restrict__ ytot,
           const float* __restrict__ norm_w, unsigned short* __restrict__ ynorm)
{
  const int row = blockIdx.x, tid = threadIdx.x;
  const int e0 = tid * 8;
  us8 zv = *(const us8*)(z + (size_t)row * DI + e0);
  f16x8 yv = *(const f16x8*)(ytot + (size_t)row * DI + e0);
  float g[8];
  float ss = 0.f;
#pragma unroll
  for (int q = 0; q < 8; ++q) {
    g[q] = (float)yv[q] * siluf(bf2f(zv[q]));
    ss += g[q] * g[q];
  }
#pragma unroll
  for (int off = 32; off > 0; off >>= 1) ss += __shfl_down(ss, off);
  __shared__ float wsum[3];
  __shared__ float sscale;
  if ((tid & 63) == 0) wsum[tid >> 6] = ss;
  __syncthreads();
  if (tid == 0) sscale = rsqrtf((wsum[0] + wsum[1] + wsum[2]) * (1.f / DI) + 1e-5f);
  __syncthreads();
  const float sc = sscale;
  us8 o;
#pragma unroll
  for (int q = 0; q < 8; ++q) o[q] = f2bf(g[q] * sc * norm_w[e0 + q]);
  *(us8*)(ynorm + (size_t)row * DI + e0) = o;
}

extern "C" void kernel_launch(void* const* d_in, const int* in_sizes, int n_in,
                              void* d_out, int out_size, void* d_ws, size_t ws_size,
                              hipStream_t stream)
{
  (void)in_sizes; (void)n_in; (void)out_size;
  const float* x       = (const float*)d_in[0];
  const float* W_in    = (const float*)d_in[1];
  const float* conv_w  = (const float*)d_in[2];
  const float* conv_b  = (const float*)d_in[3];
  const float* dt_bias = (const float*)d_in[4];
  const float* A_log   = (const float*)d_in[5];
  const float* Dp      = (const float*)d_in[6];
  const float* norm_w  = (const float*)d_in[7];
  const float* W_out   = (const float*)d_in[8];
  float* out = (float*)d_out;

  // ---- batches per pass: footprint(nb) = nb*L_*16320 + 7,385,088 ----
  const int nb = ((size_t)2 * L_ * 16320 + 7385088 <= ws_size) ? 2 : 1;
  const int rows = nb * L_;

  // ---- workspace layout (per-pass buffers) ----
  char* ws = (char*)d_ws;
  unsigned short* zseg = (unsigned short*)ws;  ws += (size_t)rows * DI * 2;   // bf16 z
  unsigned short* xbc  = (unsigned short*)ws;  ws += (size_t)rows * CD * 2;   // bf16 xBC
  _Float16* xs   = (_Float16*)ws;  ws += (size_t)rows * DI * 2;               // (ynorm home)
  _Float16* ytot = (_Float16*)ws;  ws += (size_t)rows * DI * 2;               // fp16 y
  float* Bm   = (float*)ws;  ws += (size_t)rows * DS * 4;
  float* Cm   = (float*)ws;  ws += (size_t)rows * DS * 4;
  float* dtv  = (float*)ws;  ws += (size_t)rows * H_ * 4;
  float* cumA = (float*)ws;  ws += (size_t)rows * H_ * 4;
  _Float16* Sbuf = (_Float16*)ws;  ws += (size_t)rows * 3072;  // nb*H_*NC*DS*P_*2
  unsigned short* WinT  = (unsigned short*)ws; ws += (size_t)NPJ * DM * 2;
  unsigned short* WoutT = (unsigned short*)ws; ws += (size_t)DM * DI * 2;
  float* WdtT   = (float*)ws;  ws += (size_t)H_ * DM * 4;
  unsigned short* xb    = (unsigned short*)Sbuf;     // overlay: Sbuf dead until k_intra
  unsigned short* ynorm = (unsigned short*)xs;       // overlay: xs slot free (conv fused)

  k_transpose_cast<<<dim3(24, (NPJ + 31) / 32), 256, 0, stream>>>(W_in, WinT, DM, NPJ);
  k_transpose_cast<<<dim3(48, 24), 256, 0, stream>>>(W_out, WoutT, DI, DM);
  k_wdtT<<<(H_ * DM + 255) / 256, 256, 0, stream>>>(W_in, WdtT);

  for (int b0 = 0; b0 < B_; b0 += nb) {
    const float* xp = x + (size_t)b0 * L_ * DM;

    k_dt2<<<rows / 16, 768, 0, stream>>>(xp, WdtT, dt_bias, dtv, xb);
    // in-proj: 256x128 block (512 thr), wave tile 64x64 (r6 win: 50.9us)
    k_gemm_t<256, 128, 64, 64, true><<<dim3(rows / 256, N1 / 128), 512, 0, stream>>>(
        xb, WinT, zseg, DI, DI, xbc, CD, DM);
    // slim conv: only B/C channels (DI part fused into k_intra)
    k_conv2<<<rows / CROWS, 128, 0, stream>>>(xbc, conv_w, conv_b, Bm, Cm);
    k_intra<<<dim3(NC, H_, nb), 256, 0, stream>>>(xbc, conv_w, conv_b, Bm, Cm, dtv,
                                                  A_log, Dp, cumA, ytot, Sbuf);
    k_chunkscan<<<dim3(32, H_, nb), 64, 0, stream>>>(Sbuf, cumA);
    k_inter<<<dim3(NC, H_, nb), 256, 0, stream>>>(Cm, cumA, Sbuf, ytot);
    k_rms<<<rows, 192, 0, stream>>>(zseg, ytot, norm_w, ynorm);
    // out-proj: r0-proven <128,64,64,32> -> 768 blocks = 3 even rounds on 256 CUs
    k_gemm_t<128, 64, 64, 32, false><<<dim3(rows / 128, DM / 64), 256, 0, stream>>>(
        ynorm, WoutT, out + (size_t)b0 * L_ * DM, DM, DM, out + (size_t)b0 * L_ * DM, DM, DI);
  }
}